// Round 1
// baseline (1133.988 us; speedup 1.0000x reference)
//
#include <hip/hip_runtime.h>
#include <math.h>

typedef __attribute__((ext_vector_type(8))) short bshort8;
typedef __attribute__((ext_vector_type(4))) float f32x4;

#define DI __device__ __forceinline__

DI unsigned short f2bf(float x) {
    unsigned int u = __builtin_bit_cast(unsigned int, x);
    u += 0x7fffu + ((u >> 16) & 1u);
    return (unsigned short)(u >> 16);
}

DI f32x4 mfma16(bshort8 a, bshort8 b, f32x4 c) {
    return __builtin_amdgcn_mfma_f32_16x16x32_bf16(a, b, c, 0, 0, 0);
}

// -------- composite (bilinear resize n->112, align_corners=False) then 8x8-pool weights --------
// Returns start index; fills w[0..8) (zeros where unused). Valid taps: start..start+7 clipped to <n.
DI int pool_wts(int t, int n, float* w) {
    if (n == 112) {
        #pragma unroll
        for (int i = 0; i < 8; i++) w[i] = 0.125f;
        return 8 * t;
    }
    float scale = (float)n / 112.0f;
    int lo = (int)floorf((8 * t + 0.5f) * scale - 0.5f);
    if (lo < 0) lo = 0;
    #pragma unroll
    for (int i = 0; i < 8; i++) w[i] = 0.f;
    #pragma unroll
    for (int kk = 0; kk < 8; kk++) {
        int h = 8 * t + kk;
        float s = (h + 0.5f) * scale - 0.5f;
        int j0 = (int)floorf(s);
        float f = s - (float)j0;
        if (j0 < 0) {
            w[0 - lo] += 0.125f;            // lo==0 here
        } else if (j0 >= n - 1) {
            w[(n - 1) - lo] += 0.125f;
        } else {
            w[j0 - lo]     += 0.125f * (1.f - f);
            w[j0 + 1 - lo] += 0.125f * f;
        }
    }
    return lo;
}

// -------- K1: pool all 4 scales to 14x14 (pf_s layout [cin][1568], m = b*196+t); c5 also full mean --------
__global__ __launch_bounds__(256) void pool_kernel(
    const float* __restrict__ c2, const float* __restrict__ c3,
    const float* __restrict__ c4, const float* __restrict__ c5,
    float* __restrict__ pf0, float* __restrict__ pf1,
    float* __restrict__ pf2, float* __restrict__ pf3,
    float* __restrict__ pooled)
{
    int blk = blockIdx.x;
    int sc, base, C, n;
    const float* src; float* dst;
    if (blk < 2048)       { sc = 0; base = 0;     C = 256;  n = 112; src = c2; dst = pf0; }
    else if (blk < 6144)  { sc = 1; base = 2048;  C = 512;  n = 56;  src = c3; dst = pf1; }
    else if (blk < 14336) { sc = 2; base = 6144;  C = 1024; n = 28;  src = c4; dst = pf2; }
    else                  { sc = 3; base = 14336; C = 2048; n = 14;  src = c5; dst = pf3; }
    int p = blk - base;
    int b = p / C, cin = p % C;
    const float* plane = src + (size_t)p * n * n;
    int t = threadIdx.x;

    if (t < 196) {
        int ti = t / 14, tj = t % 14;
        float wh[8], ww[8];
        int hs = pool_wts(ti, n, wh);
        int ws0 = pool_wts(tj, n, ww);
        float acc = 0.f;
        for (int i = 0; i < 8; i++) {
            int h = hs + i;
            if (h >= n) break;
            float whv = wh[i];
            const float* row = plane + (size_t)h * n;
            float racc = 0.f;
            for (int j = 0; j < 8; j++) {
                int w = ws0 + j;
                if (w >= n) break;
                racc += ww[j] * row[w];
            }
            acc += whv * racc;
        }
        dst[(size_t)cin * 1568 + b * 196 + t] = acc;
    }

    if (sc == 3) {
        __shared__ float red[256];
        float mv = (t < 196) ? plane[t] : 0.f;
        red[t] = mv;
        __syncthreads();
        for (int s2 = 128; s2 > 0; s2 >>= 1) {
            if (t < s2) red[t] += red[t + s2];
            __syncthreads();
        }
        if (t == 0) pooled[p] = red[0] / 196.f;
    }
}

// -------- K2: scale-weight MLP: sw = softmax(relu(pooled@sp_w1+b1)@sp_w2+b2); also beff --------
__global__ __launch_bounds__(512) void sw_kernel(
    const float* __restrict__ pooled,
    const float* __restrict__ sp_w1, const float* __restrict__ sp_b1,
    const float* __restrict__ sp_w2, const float* __restrict__ sp_b2,
    const float* __restrict__ lb0, const float* __restrict__ lb1,
    const float* __restrict__ lb2, const float* __restrict__ lb3,
    float* __restrict__ sw_out, float* __restrict__ beff)
{
    __shared__ float pool_s[2048];
    __shared__ float h[512];
    __shared__ float swl[4];
    int b = blockIdx.x, t = threadIdx.x;
    for (int i = t; i < 2048; i += 512) pool_s[i] = pooled[b * 2048 + i];
    __syncthreads();
    float acc = sp_b1[t];
    for (int c = 0; c < 2048; c++) acc += pool_s[c] * sp_w1[(size_t)c * 512 + t];
    h[t] = fmaxf(acc, 0.f);
    __syncthreads();
    if (t == 0) {
        float s4[4];
        for (int o = 0; o < 4; o++) {
            float a2 = sp_b2[o];
            for (int c = 0; c < 512; c++) a2 += h[c] * sp_w2[c * 4 + o];
            s4[o] = a2;
        }
        float mx = fmaxf(fmaxf(s4[0], s4[1]), fmaxf(s4[2], s4[3]));
        float e0 = expf(s4[0] - mx), e1 = expf(s4[1] - mx), e2 = expf(s4[2] - mx), e3 = expf(s4[3] - mx);
        float inv = 1.f / (e0 + e1 + e2 + e3);
        swl[0] = e0 * inv; swl[1] = e1 * inv; swl[2] = e2 * inv; swl[3] = e3 * inv;
        for (int o = 0; o < 4; o++) sw_out[b * 4 + o] = swl[o];
    }
    __syncthreads();
    if (t < 256)
        beff[b * 256 + t] = swl[0] * lb0[t] + swl[1] * lb1[t] + swl[2] * lb2[t] + swl[3] * lb3[t];
}

// -------- K3: fused lateral projections + sw-combine (bf16 MFMA), x_tok[1568][256] --------
__global__ __launch_bounds__(256) void lateral_kernel(
    const float* __restrict__ pf0, const float* __restrict__ pf1,
    const float* __restrict__ pf2, const float* __restrict__ pf3,
    const float* __restrict__ w0, const float* __restrict__ w1,
    const float* __restrict__ w2, const float* __restrict__ w3,
    const float* __restrict__ sw, const float* __restrict__ beff,
    float* __restrict__ xtok)
{
    int mt = blockIdx.x % 49, nt = blockIdx.x / 49;
    int m0 = mt * 32, n0 = nt * 64;
    __shared__ alignas(16) unsigned short As[1024];
    __shared__ alignas(16) unsigned short Bs[2048];
    int t = threadIdx.x, lane = t & 63, wid = t >> 6;
    int wm = wid >> 1, wn = wid & 1;
    f32x4 acc0 = {0, 0, 0, 0}, acc1 = {0, 0, 0, 0};

    const float* pfs[4] = {pf0, pf1, pf2, pf3};
    const float* wws[4] = {w0, w1, w2, w3};
    const int Ks[4] = {256, 512, 1024, 2048};

    int m_l = t % 32;            // A-stage: lanes along m (coalesced; pf is [k][m])
    int kqA = t / 32;            // 0..7
    int bb = (m0 + m_l) / 196;
    int k_lB = t / 8;            // B-stage: 8 lanes cover 64 n of one k-row
    int c8B = t % 8;

    for (int s = 0; s < 4; s++) {
        const float* pf = pfs[s];
        const float* W = wws[s];
        int K = Ks[s];
        float swv = sw[bb * 4 + s];
        for (int k0 = 0; k0 < K; k0 += 32) {
            #pragma unroll
            for (int i = 0; i < 4; i++) {
                int k_l = kqA * 4 + i;
                float v = pf[(size_t)(k0 + k_l) * 1568 + m0 + m_l] * swv;
                As[(m_l >> 4) * 512 + ((m_l & 15) + ((k_l >> 3) << 4)) * 8 + (k_l & 7)] = f2bf(v);
            }
            #pragma unroll
            for (int i = 0; i < 8; i++) {
                int n_l = c8B * 8 + i;
                float v = W[(size_t)(k0 + k_lB) * 256 + n0 + n_l];
                Bs[(n_l >> 4) * 512 + ((n_l & 15) + ((k_lB >> 3) << 4)) * 8 + (k_lB & 7)] = f2bf(v);
            }
            __syncthreads();
            bshort8 av = *(const bshort8*)&As[wm * 512 + lane * 8];
            bshort8 bv0 = *(const bshort8*)&Bs[(wn * 2 + 0) * 512 + lane * 8];
            bshort8 bv1 = *(const bshort8*)&Bs[(wn * 2 + 1) * 512 + lane * 8];
            acc0 = mfma16(av, bv0, acc0);
            acc1 = mfma16(av, bv1, acc1);
            __syncthreads();
        }
    }
    int col0 = n0 + wn * 32 + (lane & 15);
    int rbase = m0 + wm * 16 + ((lane >> 4) << 2);
    #pragma unroll
    for (int r = 0; r < 4; r++) {
        int m = rbase + r;
        int bb2 = m / 196;
        xtok[(size_t)m * 256 + col0]      = acc0[r] + beff[bb2 * 256 + col0];
        xtok[(size_t)m * 256 + col0 + 16] = acc1[r] + beff[bb2 * 256 + col0 + 16];
    }
}

// -------- generic bf16-MFMA GEMM: C[m,n] = alpha * sum_k A[m,k]*B + bias --------
// A: [m][k] row-major (lda). B_IS_KXN: B is [k][n] (ldb); else B is [n][k] (ldb).
// Block tile 32m x 64n, 4 waves (2x2), K-chunk 32. Batched via grid.y/z strides.
template <bool B_IS_KXN>
__global__ __launch_bounds__(256) void gemm_kernel(
    const float* __restrict__ Ab, int lda, long long sAy, long long sAz,
    const float* __restrict__ Bb, int ldb, long long sBy, long long sBz,
    float* __restrict__ Cb, int ldc, long long sCy, long long sCz,
    const float* __restrict__ bias, int M, int N, int K,
    float alpha, int mtiles)
{
    const float* A = Ab + blockIdx.y * sAy + blockIdx.z * sAz;
    const float* B = Bb + blockIdx.y * sBy + blockIdx.z * sBz;
    float* C = Cb + blockIdx.y * sCy + blockIdx.z * sCz;
    int mt = blockIdx.x % mtiles, nt = blockIdx.x / mtiles;
    int m0 = mt * 32, n0 = nt * 64;
    __shared__ alignas(16) unsigned short As[1024];
    __shared__ alignas(16) unsigned short Bs[2048];
    int t = threadIdx.x, lane = t & 63, wid = t >> 6;
    int wm = wid >> 1, wn = wid & 1;
    f32x4 acc0 = {0, 0, 0, 0}, acc1 = {0, 0, 0, 0};

    for (int k0 = 0; k0 < K; k0 += 32) {
        {   // stage A: thread t -> row m_l = t/8, k-quad kq = t%8 (coalesced 128B per 8 lanes)
            int m_l = t / 8, kq = t % 8;
            int m = m0 + m_l;
            #pragma unroll
            for (int i = 0; i < 4; i++) {
                int k_l = kq * 4 + i;
                int k = k0 + k_l;
                float v = (m < M && k < K) ? A[(size_t)m * lda + k] : 0.f;
                As[(m_l >> 4) * 512 + ((m_l & 15) + ((k_l >> 3) << 4)) * 8 + (k_l & 7)] = f2bf(v);
            }
        }
        if constexpr (B_IS_KXN) {
            int k_l = t / 8, c8 = t % 8;
            int k = k0 + k_l;
            #pragma unroll
            for (int i = 0; i < 8; i++) {
                int n_l = c8 * 8 + i;
                int n = n0 + n_l;
                float v = (k < K && n < N) ? B[(size_t)k * ldb + n] : 0.f;
                Bs[(n_l >> 4) * 512 + ((n_l & 15) + ((k_l >> 3) << 4)) * 8 + (k_l & 7)] = f2bf(v);
            }
        } else {
            #pragma unroll
            for (int g = 0; g < 2; g++) {
                int n_l = (t / 8) + 32 * g;
                int kq = t % 8;
                int n = n0 + n_l;
                #pragma unroll
                for (int i = 0; i < 4; i++) {
                    int k_l = kq * 4 + i;
                    int k = k0 + k_l;
                    float v = (n < N && k < K) ? B[(size_t)n * ldb + k] : 0.f;
                    Bs[(n_l >> 4) * 512 + ((n_l & 15) + ((k_l >> 3) << 4)) * 8 + (k_l & 7)] = f2bf(v);
                }
            }
        }
        __syncthreads();
        bshort8 av = *(const bshort8*)&As[wm * 512 + lane * 8];
        bshort8 bv0 = *(const bshort8*)&Bs[(wn * 2 + 0) * 512 + lane * 8];
        bshort8 bv1 = *(const bshort8*)&Bs[(wn * 2 + 1) * 512 + lane * 8];
        acc0 = mfma16(av, bv0, acc0);
        acc1 = mfma16(av, bv1, acc1);
        __syncthreads();
    }
    int col0 = n0 + wn * 32 + (lane & 15);
    int rbase = m0 + wm * 16 + ((lane >> 4) << 2);
    #pragma unroll
    for (int r = 0; r < 4; r++) {
        int m = rbase + r;
        if (m < M) {
            if (col0 < N) {
                float v = acc0[r] * alpha;
                if (bias) v += bias[col0];
                C[(size_t)m * ldc + col0] = v;
            }
            int c1 = col0 + 16;
            if (c1 < N) {
                float v = acc1[r] * alpha;
                if (bias) v += bias[c1];
                C[(size_t)m * ldc + c1] = v;
            }
        }
    }
}

// -------- attention softmax over rows of S [12544][196], in place --------
__global__ __launch_bounds__(256) void attn_softmax(float* __restrict__ S)
{
    int wid = threadIdx.x >> 6, lane = threadIdx.x & 63;
    size_t row = (size_t)blockIdx.x * 4 + wid;
    float* p = S + row * 196;
    float v0 = p[lane];
    float v1 = p[64 + lane];
    float v2 = p[128 + lane];
    float v3 = (lane < 4) ? p[192 + lane] : -1e30f;
    float mx = fmaxf(fmaxf(v0, v1), fmaxf(v2, v3));
    #pragma unroll
    for (int off = 32; off > 0; off >>= 1) mx = fmaxf(mx, __shfl_xor(mx, off, 64));
    float e0 = expf(v0 - mx), e1 = expf(v1 - mx), e2 = expf(v2 - mx);
    float e3 = (lane < 4) ? expf(v3 - mx) : 0.f;
    float sum = e0 + e1 + e2 + e3;
    #pragma unroll
    for (int off = 32; off > 0; off >>= 1) sum += __shfl_xor(sum, off, 64);
    float inv = 1.f / sum;
    p[lane] = e0 * inv;
    p[64 + lane] = e1 * inv;
    p[128 + lane] = e2 * inv;
    if (lane < 4) p[192 + lane] = e3 * inv;
}

// -------- post-proj: gctx = token-mean; lf = label_emb + gctx --------
__global__ __launch_bounds__(256) void projpost_kernel(
    const float* __restrict__ proj, const float* __restrict__ lemb, float* __restrict__ lf)
{
    int b = blockIdx.x, c = threadIdx.x;
    float sum = 0.f;
    for (int n = 0; n < 196; n++) sum += proj[((size_t)b * 196 + n) * 256 + c];
    float g = sum / 196.f;
    for (int l = 0; l < 80; l++)
        lf[((size_t)b * 80 + l) * 256 + c] = lemb[l * 256 + c] + g;
}

// -------- GAT attention scores -> atts (output 6) --------
__global__ __launch_bounds__(256) void gat_scores(
    const float* __restrict__ Wx, const float* __restrict__ gat_a, float* __restrict__ atts)
{
    int b = blockIdx.x, h = blockIdx.y, t = threadIdx.x;
    __shared__ float s1[80], s2[80];
    if (t < 160) {
        int which = t / 80, l = t % 80;
        const float* row = Wx + ((size_t)h * 640 + b * 80 + l) * 256;
        const float* av = gat_a + h * 512 + which * 256;
        float acc = 0.f;
        for (int c = 0; c < 256; c++) acc += row[c] * av[c];
        if (which) s2[l] = acc; else s1[l] = acc;
    }
    __syncthreads();
    if (t < 80) {
        float si = s1[t];
        float mx = -1e30f;
        for (int j = 0; j < 80; j++) {
            float v = si + s2[j];
            v = v > 0.f ? v : 0.2f * v;
            mx = fmaxf(mx, v);
        }
        float sum = 0.f;
        for (int j = 0; j < 80; j++) {
            float v = si + s2[j];
            v = v > 0.f ? v : 0.2f * v;
            sum += expf(v - mx);
        }
        float inv = 1.f / sum;
        float* orow = atts + (size_t)h * 51200 + b * 6400 + t * 80;
        for (int j = 0; j < 80; j++) {
            float v = si + s2[j];
            v = v > 0.f ? v : 0.2f * v;
            orow[j] = expf(v - mx) * inv;
        }
    }
}

// -------- agg = mean over labels --------
__global__ __launch_bounds__(256) void agg_kernel(const float* __restrict__ graph, float* __restrict__ agg)
{
    int b = blockIdx.x, c = threadIdx.x;
    float sum = 0.f;
    for (int l = 0; l < 80; l++) sum += graph[((size_t)b * 80 + l) * 256 + c];
    agg[b * 256 + c] = sum / 80.f;
}

// -------- final heads: logits/spec/spat/gate/unc (outputs 0..4) --------
__global__ __launch_bounds__(256) void final_kernel(
    const float* __restrict__ agg,
    const float* __restrict__ spec_w1, const float* __restrict__ spec_b1,
    const float* __restrict__ spec_w2, const float* __restrict__ spec_b2,
    const float* __restrict__ spat_w1, const float* __restrict__ spat_b1,
    const float* __restrict__ spat_w2, const float* __restrict__ spat_b2,
    const float* __restrict__ gate_w, const float* __restrict__ gate_b,
    const float* __restrict__ unc_w, const float* __restrict__ unc_b,
    float* __restrict__ out)
{
    int b = blockIdx.x, t = threadIdx.x;
    __shared__ float a_s[256], h1[128], h2[128], alph[80];
    a_s[t] = agg[b * 256 + t];
    __syncthreads();
    if (t < 128) {
        float acc1 = spec_b1[t], acc2 = spat_b1[t];
        for (int c = 0; c < 256; c++) {
            acc1 += a_s[c] * spec_w1[c * 128 + t];
            acc2 += a_s[c] * spat_w1[c * 128 + t];
        }
        h1[t] = fmaxf(acc1, 0.f);
        h2[t] = fmaxf(acc2, 0.f);
    }
    __syncthreads();
    if (t < 80) {
        float sp = spec_b2[t], st = spat_b2[t];
        for (int c = 0; c < 128; c++) {
            sp += h1[c] * spec_w2[c * 80 + t];
            st += h2[c] * spat_w2[c * 80 + t];
        }
        float gz = gate_b[t], uz = unc_b[t];
        for (int c = 0; c < 256; c++) {
            gz += a_s[c] * gate_w[c * 80 + t];
            uz += a_s[c] * unc_w[c * 80 + t];
        }
        float g = 1.f / (1.f + expf(-gz));
        alph[t] = log1pf(expf(uz)) + 1.f;
        out[b * 80 + t] = g * sp + (1.f - g) * st;
        out[640 + b * 80 + t] = sp;
        out[1280 + b * 80 + t] = st;
        out[1920 + b * 80 + t] = g;
    }
    __syncthreads();
    if (t == 0) {
        float s = 0.f;
        for (int l = 0; l < 80; l++) s += alph[l];
        out[2560 + b] = 80.f / s;
    }
}

// ---------------- launcher ----------------
extern "C" void kernel_launch(void* const* d_in, const int* in_sizes, int n_in,
                              void* d_out, int out_size, void* d_ws, size_t ws_size,
                              hipStream_t stream)
{
    (void)in_sizes; (void)n_in; (void)out_size; (void)ws_size;
    const float* c2 = (const float*)d_in[0];
    const float* c3 = (const float*)d_in[1];
    const float* c4 = (const float*)d_in[2];
    const float* c5 = (const float*)d_in[3];
    const float* lat_w0 = (const float*)d_in[4];
    const float* lat_b0 = (const float*)d_in[5];
    const float* lat_w1 = (const float*)d_in[6];
    const float* lat_b1 = (const float*)d_in[7];
    const float* lat_w2 = (const float*)d_in[8];
    const float* lat_b2 = (const float*)d_in[9];
    const float* lat_w3 = (const float*)d_in[10];
    const float* lat_b3 = (const float*)d_in[11];
    const float* sp_w1 = (const float*)d_in[12];
    const float* sp_b1 = (const float*)d_in[13];
    const float* sp_w2 = (const float*)d_in[14];
    const float* sp_b2 = (const float*)d_in[15];
    const float* qkv_w = (const float*)d_in[16];
    const float* qkv_b = (const float*)d_in[17];
    const float* proj_w = (const float*)d_in[18];
    const float* proj_b = (const float*)d_in[19];
    const float* gat_W = (const float*)d_in[20];
    const float* gat_a = (const float*)d_in[21];
    const float* out_w = (const float*)d_in[22];
    const float* out_b = (const float*)d_in[23];
    const float* label_emb = (const float*)d_in[24];
    const float* spec_w1 = (const float*)d_in[25];
    const float* spec_b1 = (const float*)d_in[26];
    const float* spec_w2 = (const float*)d_in[27];
    const float* spec_b2 = (const float*)d_in[28];
    const float* spat_w1 = (const float*)d_in[29];
    const float* spat_b1 = (const float*)d_in[30];
    const float* spat_w2 = (const float*)d_in[31];
    const float* spat_b2 = (const float*)d_in[32];
    const float* gate_w = (const float*)d_in[33];
    const float* gate_b = (const float*)d_in[34];
    const float* unc_w = (const float*)d_in[35];
    const float* unc_b = (const float*)d_in[36];

    float* out = (float*)d_out;
    float* ws = (float*)d_ws;

    // workspace layout (floats); phase-2 buffers reuse the (dead) pf region
    float* pf0    = ws + 0;        // 401408
    float* pf1    = ws + 401408;   // 802816
    float* pf2    = ws + 1204224;  // 1605632
    float* pf3    = ws + 2809856;  // 3211264
    float* pooled = ws + 6021120;  // 16384
    float* beff   = ws + 6037504;  // 2048
    float* qkv    = ws + 0;        // 1204224 (reuses pf0/pf1)
    float* S      = ws + 1204224;  // 2458624 (reuses pf2/pf3)
    float* xo     = ws + 3662848;  // 401408
    float* proj   = ws + 4064256;  // 401408
    float* lf     = ws + 4465664;  // 163840
    float* Wx     = ws + 4629504;  // 655360
    float* concat = ws + 5284864;  // 655360
    float* graph  = ws + 5940224;  // 163840
    float* aggp   = ws + 6104064;  // 2048
    float* xtok   = ws + 6106112;  // 401408  (total 6507520 floats = 26.0 MB)

    float* swp  = out + 2568;  // sw [8,4] (output 5)
    float* atts = out + 2600;  // atts [4,8,80,80] (output 6)

    // 1. pool features of all scales to 14x14 (+ c5 global mean)
    pool_kernel<<<30720, 256, 0, stream>>>(c2, c3, c4, c5, pf0, pf1, pf2, pf3, pooled);
    // 2. scale weights + effective bias
    sw_kernel<<<8, 512, 0, stream>>>(pooled, sp_w1, sp_b1, sp_w2, sp_b2,
                                     lat_b0, lat_b1, lat_b2, lat_b3, swp, beff);
    // 3. fused lateral projection + sw combine -> x tokens [1568,256]
    lateral_kernel<<<196, 256, 0, stream>>>(pf0, pf1, pf2, pf3,
                                            lat_w0, lat_w1, lat_w2, lat_w3,
                                            swp, beff, xtok);
    // 4. qkv = x @ qkv_w + qkv_b : [1568,768]
    gemm_kernel<true><<<dim3(49 * 12, 1, 1), 256, 0, stream>>>(
        xtok, 256, 0, 0, qkv_w, 768, 0, 0, qkv, 768, 0, 0,
        qkv_b, 1568, 768, 256, 1.f, 49);
    // 5. S = q @ k^T * hd^-0.5, per (b,h) : [64,196,196]
    gemm_kernel<false><<<dim3(7 * 4, 8, 8), 256, 0, stream>>>(
        qkv, 768, 150528, 32, qkv + 256, 768, 150528, 32,
        S, 196, 307328, 38416, nullptr, 196, 196, 32, 0.17677669529663687f, 7);
    // 6. row softmax on S (in place)
    attn_softmax<<<3136, 256, 0, stream>>>(S);
    // 7. xo = P @ v : [1568,256] (head-concat layout)
    gemm_kernel<true><<<dim3(7, 8, 8), 256, 0, stream>>>(
        S, 196, 307328, 38416, qkv + 512, 768, 150528, 32,
        xo, 256, 50176, 32, nullptr, 196, 32, 196, 1.f, 7);
    // 8. proj
    gemm_kernel<true><<<dim3(49 * 4, 1, 1), 256, 0, stream>>>(
        xo, 256, 0, 0, proj_w, 256, 0, 0, proj, 256, 0, 0,
        proj_b, 1568, 256, 256, 1.f, 49);
    // 9. gctx + lf
    projpost_kernel<<<8, 256, 0, stream>>>(proj, label_emb, lf);
    // 10. Wx[h] = lf @ gat_W[h] : [4,640,256]
    gemm_kernel<true><<<dim3(20 * 4, 1, 4), 256, 0, stream>>>(
        lf, 256, 0, 0, gat_W, 256, 0, 65536, Wx, 256, 0, 163840,
        nullptr, 640, 256, 256, 1.f, 20);
    // 11. GAT attention -> atts (output 6)
    gat_scores<<<dim3(8, 4), 256, 0, stream>>>(Wx, gat_a, atts);
    // 12. heads = atts @ Wx, written directly in concat layout [640,1024]
    gemm_kernel<true><<<dim3(3 * 4, 8, 4), 256, 0, stream>>>(
        atts, 80, 6400, 51200, Wx, 256, 20480, 163840,
        concat, 1024, 81920, 256, nullptr, 80, 256, 80, 1.f, 3);
    // 13. graph = concat @ out_w + out_b
    gemm_kernel<true><<<dim3(20 * 4, 1, 1), 256, 0, stream>>>(
        concat, 1024, 0, 0, out_w, 256, 0, 0, graph, 256, 0, 0,
        out_b, 640, 256, 1024, 1.f, 20);
    // 14. agg = label-mean
    agg_kernel<<<8, 256, 0, stream>>>(graph, aggp);
    // 15. final heads -> outputs 0..4
    final_kernel<<<8, 256, 0, stream>>>(aggp,
        spec_w1, spec_b1, spec_w2, spec_b2,
        spat_w1, spat_b1, spat_w2, spat_b2,
        gate_w, gate_b, unc_w, unc_b, out);
}

// Round 2
// 854.877 us; speedup vs baseline: 1.3265x; 1.3265x over previous
//
#include <hip/hip_runtime.h>
#include <math.h>

typedef __attribute__((ext_vector_type(8))) short bshort8;
typedef __attribute__((ext_vector_type(4))) float f32x4;

#define DI __device__ __forceinline__

DI unsigned short f2bf(float x) {
    unsigned int u = __builtin_bit_cast(unsigned int, x);
    u += 0x7fffu + ((u >> 16) & 1u);
    return (unsigned short)(u >> 16);
}

DI f32x4 mfma16(bshort8 a, bshort8 b, f32x4 c) {
    return __builtin_amdgcn_mfma_f32_16x16x32_bf16(a, b, c, 0, 0, 0);
}

// -------- composite (bilinear resize n->112, align_corners=False) then 8x8-pool weights --------
DI int pool_wts(int t, int n, float* w) {
    if (n == 112) {
        #pragma unroll
        for (int i = 0; i < 8; i++) w[i] = 0.125f;
        return 8 * t;
    }
    float scale = (float)n / 112.0f;
    int lo = (int)floorf((8 * t + 0.5f) * scale - 0.5f);
    if (lo < 0) lo = 0;
    #pragma unroll
    for (int i = 0; i < 8; i++) w[i] = 0.f;
    #pragma unroll
    for (int kk = 0; kk < 8; kk++) {
        int h = 8 * t + kk;
        float s = (h + 0.5f) * scale - 0.5f;
        int j0 = (int)floorf(s);
        float f = s - (float)j0;
        if (j0 < 0) {
            w[0 - lo] += 0.125f;
        } else if (j0 >= n - 1) {
            w[(n - 1) - lo] += 0.125f;
        } else {
            w[j0 - lo]     += 0.125f * (1.f - f);
            w[j0 + 1 - lo] += 0.125f * f;
        }
    }
    return lo;
}

// -------- K1: LDS-staged pooling, one block per (b,cin) plane --------
template <int N>
__global__ __launch_bounds__(256) void pool_scale(
    const float* __restrict__ src, float* __restrict__ dst,
    float* __restrict__ pooled, int C)
{
    constexpr int NN = N * N;
    __shared__ float sm[NN];
    int p = blockIdx.x;
    int b = p / C, cin = p % C;
    const float* plane = src + (size_t)p * NN;
    int t = threadIdx.x;
    const float4* p4 = (const float4*)plane;
    for (int i = t; i < NN / 4; i += 256) ((float4*)sm)[i] = p4[i];
    __syncthreads();
    if (t < 196) {
        int ti = t / 14, tj = t % 14;
        float acc;
        if constexpr (N == 112) {
            const float4* s4 = (const float4*)sm;
            float a = 0.f;
            #pragma unroll
            for (int i = 0; i < 8; i++) {
                int base = ((8 * ti + i) * 112 + 8 * tj) >> 2;
                float4 u = s4[base];
                float4 v = s4[base + 1];
                a += (u.x + u.y) + (u.z + u.w) + (v.x + v.y) + (v.z + v.w);
            }
            acc = a * (1.f / 64.f);
        } else {
            float wh[8], ww[8];
            int hs = pool_wts(ti, N, wh);
            int ws0 = pool_wts(tj, N, ww);
            acc = 0.f;
            for (int i = 0; i < 8; i++) {
                int h = hs + i;
                if (h >= N) break;
                const float* row = sm + h * N;
                float r = 0.f;
                for (int j = 0; j < 8; j++) {
                    int w = ws0 + j;
                    if (w >= N) break;
                    r += ww[j] * row[w];
                }
                acc += wh[i] * r;
            }
        }
        dst[(size_t)cin * 1568 + b * 196 + t] = acc;
    }
    if constexpr (N == 14) {
        __shared__ float red[256];
        red[t] = (t < 196) ? sm[t] : 0.f;
        __syncthreads();
        for (int s2 = 128; s2 > 0; s2 >>= 1) {
            if (t < s2) red[t] += red[t + s2];
            __syncthreads();
        }
        if (t == 0) pooled[p] = red[0] * (1.f / 196.f);
    }
}

// -------- K2a: partial GEMV for scale-weight MLP layer 1 (split-K) --------
__global__ __launch_bounds__(512) void sw_part(
    const float* __restrict__ pooled, const float* __restrict__ sp_w1,
    float* __restrict__ partial)
{
    int b = blockIdx.x, kc = blockIdx.y, t = threadIdx.x;
    __shared__ float ps[256];
    if (t < 256) ps[t] = pooled[b * 2048 + kc * 256 + t];
    __syncthreads();
    float acc = 0.f;
    const float* w = sp_w1 + (size_t)(kc * 256) * 512 + t;
    #pragma unroll 4
    for (int c = 0; c < 256; c++) acc += ps[c] * w[(size_t)c * 512];
    partial[((size_t)b * 8 + kc) * 512 + t] = acc;
}

// -------- K2b: finish sw MLP: relu -> layer2 -> softmax -> sw, beff --------
__global__ __launch_bounds__(512) void sw_fin(
    const float* __restrict__ partial, const float* __restrict__ sp_b1,
    const float* __restrict__ sp_w2, const float* __restrict__ sp_b2,
    const float* __restrict__ lb0, const float* __restrict__ lb1,
    const float* __restrict__ lb2, const float* __restrict__ lb3,
    float* __restrict__ sw_out, float* __restrict__ beff)
{
    int b = blockIdx.x, t = threadIdx.x;
    __shared__ float h[512];
    __shared__ float s4s[4];
    __shared__ float swl[4];
    float a = sp_b1[t];
    #pragma unroll
    for (int kc = 0; kc < 8; kc++) a += partial[((size_t)b * 8 + kc) * 512 + t];
    h[t] = fmaxf(a, 0.f);
    __syncthreads();
    int wv = t >> 6, lane = t & 63;
    if (wv < 4) {
        float acc = 0.f;
        #pragma unroll
        for (int i = 0; i < 8; i++) {
            int idx = lane + 64 * i;
            acc += h[idx] * sp_w2[idx * 4 + wv];
        }
        #pragma unroll
        for (int off = 32; off > 0; off >>= 1) acc += __shfl_xor(acc, off, 64);
        if (lane == 0) s4s[wv] = acc + sp_b2[wv];
    }
    __syncthreads();
    if (t == 0) {
        float mx = fmaxf(fmaxf(s4s[0], s4s[1]), fmaxf(s4s[2], s4s[3]));
        float e0 = expf(s4s[0] - mx), e1 = expf(s4s[1] - mx);
        float e2 = expf(s4s[2] - mx), e3 = expf(s4s[3] - mx);
        float inv = 1.f / (e0 + e1 + e2 + e3);
        swl[0] = e0 * inv; swl[1] = e1 * inv; swl[2] = e2 * inv; swl[3] = e3 * inv;
        for (int o = 0; o < 4; o++) sw_out[b * 4 + o] = swl[o];
    }
    __syncthreads();
    if (t < 256)
        beff[b * 256 + t] = swl[0] * lb0[t] + swl[1] * lb1[t] + swl[2] * lb2[t] + swl[3] * lb3[t];
}

// -------- K3a: init xtok with effective bias --------
__global__ __launch_bounds__(256) void xtok_init(
    const float* __restrict__ beff, float* __restrict__ xtok)
{
    int m = blockIdx.x, c = threadIdx.x;
    xtok[(size_t)m * 256 + c] = beff[(m / 196) * 256 + c];
}

// -------- K3b: lateral projection, K split into 8 slices, atomic accumulate --------
__global__ __launch_bounds__(256) void lateral_slice(
    const float* __restrict__ pf0, const float* __restrict__ pf1,
    const float* __restrict__ pf2, const float* __restrict__ pf3,
    const float* __restrict__ w0, const float* __restrict__ w1,
    const float* __restrict__ w2, const float* __restrict__ w3,
    const float* __restrict__ sw, float* __restrict__ xtok)
{
    const int sArr[8]   = {0, 1, 2, 2, 3, 3, 3, 3};
    const int koffArr[8] = {0, 0, 0, 512, 0, 512, 1024, 1536};
    const int klenArr[8] = {256, 512, 512, 512, 512, 512, 512, 512};
    int sl = blockIdx.y;
    int s = sArr[sl], koff = koffArr[sl], klen = klenArr[sl];
    const float* pf = (s == 0) ? pf0 : (s == 1) ? pf1 : (s == 2) ? pf2 : pf3;
    const float* W  = (s == 0) ? w0  : (s == 1) ? w1  : (s == 2) ? w2  : w3;

    int mt = blockIdx.x % 49, nt = blockIdx.x / 49;
    int m0 = mt * 32, n0 = nt * 64;
    __shared__ alignas(16) unsigned short As[1024];
    __shared__ alignas(16) unsigned short Bs[2048];
    int t = threadIdx.x, lane = t & 63, wid = t >> 6;
    int wm = wid >> 1, wn = wid & 1;
    f32x4 acc0 = {0, 0, 0, 0}, acc1 = {0, 0, 0, 0};

    int m_l = t % 32;
    int kqA = t / 32;
    int bb = (m0 + m_l) / 196;
    int k_lB = t / 8;
    int c8B = t % 8;
    float swv = sw[bb * 4 + s];

    for (int k0 = 0; k0 < klen; k0 += 32) {
        #pragma unroll
        for (int i = 0; i < 4; i++) {
            int k_l = kqA * 4 + i;
            float v = pf[(size_t)(koff + k0 + k_l) * 1568 + m0 + m_l] * swv;
            As[(m_l >> 4) * 512 + ((m_l & 15) + ((k_l >> 3) << 4)) * 8 + (k_l & 7)] = f2bf(v);
        }
        #pragma unroll
        for (int i = 0; i < 8; i++) {
            int n_l = c8B * 8 + i;
            float v = W[(size_t)(koff + k0 + k_lB) * 256 + n0 + n_l];
            Bs[(n_l >> 4) * 512 + ((n_l & 15) + ((k_lB >> 3) << 4)) * 8 + (k_lB & 7)] = f2bf(v);
        }
        __syncthreads();
        bshort8 av = *(const bshort8*)&As[wm * 512 + lane * 8];
        bshort8 bv0 = *(const bshort8*)&Bs[(wn * 2 + 0) * 512 + lane * 8];
        bshort8 bv1 = *(const bshort8*)&Bs[(wn * 2 + 1) * 512 + lane * 8];
        acc0 = mfma16(av, bv0, acc0);
        acc1 = mfma16(av, bv1, acc1);
        __syncthreads();
    }
    int col0 = n0 + wn * 32 + (lane & 15);
    int rbase = m0 + wm * 16 + ((lane >> 4) << 2);
    #pragma unroll
    for (int r = 0; r < 4; r++) {
        int m = rbase + r;
        atomicAdd(&xtok[(size_t)m * 256 + col0], acc0[r]);
        atomicAdd(&xtok[(size_t)m * 256 + col0 + 16], acc1[r]);
    }
}

// -------- generic bf16-MFMA GEMM --------
template <bool B_IS_KXN>
__global__ __launch_bounds__(256) void gemm_kernel(
    const float* __restrict__ Ab, int lda, long long sAy, long long sAz,
    const float* __restrict__ Bb, int ldb, long long sBy, long long sBz,
    float* __restrict__ Cb, int ldc, long long sCy, long long sCz,
    const float* __restrict__ bias, int M, int N, int K,
    float alpha, int mtiles)
{
    const float* A = Ab + blockIdx.y * sAy + blockIdx.z * sAz;
    const float* B = Bb + blockIdx.y * sBy + blockIdx.z * sBz;
    float* C = Cb + blockIdx.y * sCy + blockIdx.z * sCz;
    int mt = blockIdx.x % mtiles, nt = blockIdx.x / mtiles;
    int m0 = mt * 32, n0 = nt * 64;
    __shared__ alignas(16) unsigned short As[1024];
    __shared__ alignas(16) unsigned short Bs[2048];
    int t = threadIdx.x, lane = t & 63, wid = t >> 6;
    int wm = wid >> 1, wn = wid & 1;
    f32x4 acc0 = {0, 0, 0, 0}, acc1 = {0, 0, 0, 0};

    for (int k0 = 0; k0 < K; k0 += 32) {
        {
            int m_l = t / 8, kq = t % 8;
            int m = m0 + m_l;
            #pragma unroll
            for (int i = 0; i < 4; i++) {
                int k_l = kq * 4 + i;
                int k = k0 + k_l;
                float v = (m < M && k < K) ? A[(size_t)m * lda + k] : 0.f;
                As[(m_l >> 4) * 512 + ((m_l & 15) + ((k_l >> 3) << 4)) * 8 + (k_l & 7)] = f2bf(v);
            }
        }
        if constexpr (B_IS_KXN) {
            int k_l = t / 8, c8 = t % 8;
            int k = k0 + k_l;
            #pragma unroll
            for (int i = 0; i < 8; i++) {
                int n_l = c8 * 8 + i;
                int n = n0 + n_l;
                float v = (k < K && n < N) ? B[(size_t)k * ldb + n] : 0.f;
                Bs[(n_l >> 4) * 512 + ((n_l & 15) + ((k_l >> 3) << 4)) * 8 + (k_l & 7)] = f2bf(v);
            }
        } else {
            #pragma unroll
            for (int g = 0; g < 2; g++) {
                int n_l = (t / 8) + 32 * g;
                int kq = t % 8;
                int n = n0 + n_l;
                #pragma unroll
                for (int i = 0; i < 4; i++) {
                    int k_l = kq * 4 + i;
                    int k = k0 + k_l;
                    float v = (n < N && k < K) ? B[(size_t)n * ldb + k] : 0.f;
                    Bs[(n_l >> 4) * 512 + ((n_l & 15) + ((k_l >> 3) << 4)) * 8 + (k_l & 7)] = f2bf(v);
                }
            }
        }
        __syncthreads();
        bshort8 av = *(const bshort8*)&As[wm * 512 + lane * 8];
        bshort8 bv0 = *(const bshort8*)&Bs[(wn * 2 + 0) * 512 + lane * 8];
        bshort8 bv1 = *(const bshort8*)&Bs[(wn * 2 + 1) * 512 + lane * 8];
        acc0 = mfma16(av, bv0, acc0);
        acc1 = mfma16(av, bv1, acc1);
        __syncthreads();
    }
    int col0 = n0 + wn * 32 + (lane & 15);
    int rbase = m0 + wm * 16 + ((lane >> 4) << 2);
    #pragma unroll
    for (int r = 0; r < 4; r++) {
        int m = rbase + r;
        if (m < M) {
            if (col0 < N) {
                float v = acc0[r] * alpha;
                if (bias) v += bias[col0];
                C[(size_t)m * ldc + col0] = v;
            }
            int c1 = col0 + 16;
            if (c1 < N) {
                float v = acc1[r] * alpha;
                if (bias) v += bias[c1];
                C[(size_t)m * ldc + c1] = v;
            }
        }
    }
}

// -------- attention softmax over rows of S [12544][196], in place --------
__global__ __launch_bounds__(256) void attn_softmax(float* __restrict__ S)
{
    int wid = threadIdx.x >> 6, lane = threadIdx.x & 63;
    size_t row = (size_t)blockIdx.x * 4 + wid;
    float* p = S + row * 196;
    float v0 = p[lane];
    float v1 = p[64 + lane];
    float v2 = p[128 + lane];
    float v3 = (lane < 4) ? p[192 + lane] : -1e30f;
    float mx = fmaxf(fmaxf(v0, v1), fmaxf(v2, v3));
    #pragma unroll
    for (int off = 32; off > 0; off >>= 1) mx = fmaxf(mx, __shfl_xor(mx, off, 64));
    float e0 = expf(v0 - mx), e1 = expf(v1 - mx), e2 = expf(v2 - mx);
    float e3 = (lane < 4) ? expf(v3 - mx) : 0.f;
    float sum = e0 + e1 + e2 + e3;
    #pragma unroll
    for (int off = 32; off > 0; off >>= 1) sum += __shfl_xor(sum, off, 64);
    float inv = 1.f / sum;
    p[lane] = e0 * inv;
    p[64 + lane] = e1 * inv;
    p[128 + lane] = e2 * inv;
    if (lane < 4) p[192 + lane] = e3 * inv;
}

// -------- post-proj: gctx = token-mean; lf = label_emb + gctx --------
__global__ __launch_bounds__(256) void projpost_kernel(
    const float* __restrict__ proj, const float* __restrict__ lemb, float* __restrict__ lf)
{
    int b = blockIdx.x, c = threadIdx.x;
    float sum = 0.f;
    for (int n = 0; n < 196; n++) sum += proj[((size_t)b * 196 + n) * 256 + c];
    float g = sum / 196.f;
    for (int l = 0; l < 80; l++)
        lf[((size_t)b * 80 + l) * 256 + c] = lemb[l * 256 + c] + g;
}

// -------- GAT attention scores -> atts (output 6) --------
__global__ __launch_bounds__(256) void gat_scores(
    const float* __restrict__ Wx, const float* __restrict__ gat_a, float* __restrict__ atts)
{
    int b = blockIdx.x, h = blockIdx.y, t = threadIdx.x;
    __shared__ float s1[80], s2[80];
    if (t < 160) {
        int which = t / 80, l = t % 80;
        const float* row = Wx + ((size_t)h * 640 + b * 80 + l) * 256;
        const float* av = gat_a + h * 512 + which * 256;
        float acc = 0.f;
        for (int c = 0; c < 256; c++) acc += row[c] * av[c];
        if (which) s2[l] = acc; else s1[l] = acc;
    }
    __syncthreads();
    if (t < 80) {
        float si = s1[t];
        float mx = -1e30f;
        for (int j = 0; j < 80; j++) {
            float v = si + s2[j];
            v = v > 0.f ? v : 0.2f * v;
            mx = fmaxf(mx, v);
        }
        float sum = 0.f;
        for (int j = 0; j < 80; j++) {
            float v = si + s2[j];
            v = v > 0.f ? v : 0.2f * v;
            sum += expf(v - mx);
        }
        float inv = 1.f / sum;
        float* orow = atts + (size_t)h * 51200 + b * 6400 + t * 80;
        for (int j = 0; j < 80; j++) {
            float v = si + s2[j];
            v = v > 0.f ? v : 0.2f * v;
            orow[j] = expf(v - mx) * inv;
        }
    }
}

// -------- agg = mean over labels --------
__global__ __launch_bounds__(256) void agg_kernel(const float* __restrict__ graph, float* __restrict__ agg)
{
    int b = blockIdx.x, c = threadIdx.x;
    float sum = 0.f;
    for (int l = 0; l < 80; l++) sum += graph[((size_t)b * 80 + l) * 256 + c];
    agg[b * 256 + c] = sum / 80.f;
}

// -------- final heads --------
__global__ __launch_bounds__(256) void final_kernel(
    const float* __restrict__ agg,
    const float* __restrict__ spec_w1, const float* __restrict__ spec_b1,
    const float* __restrict__ spec_w2, const float* __restrict__ spec_b2,
    const float* __restrict__ spat_w1, const float* __restrict__ spat_b1,
    const float* __restrict__ spat_w2, const float* __restrict__ spat_b2,
    const float* __restrict__ gate_w, const float* __restrict__ gate_b,
    const float* __restrict__ unc_w, const float* __restrict__ unc_b,
    float* __restrict__ out)
{
    int b = blockIdx.x, t = threadIdx.x;
    __shared__ float a_s[256], h1[128], h2[128], alph[80];
    a_s[t] = agg[b * 256 + t];
    __syncthreads();
    if (t < 128) {
        float acc1 = spec_b1[t], acc2 = spat_b1[t];
        for (int c = 0; c < 256; c++) {
            acc1 += a_s[c] * spec_w1[c * 128 + t];
            acc2 += a_s[c] * spat_w1[c * 128 + t];
        }
        h1[t] = fmaxf(acc1, 0.f);
        h2[t] = fmaxf(acc2, 0.f);
    }
    __syncthreads();
    if (t < 80) {
        float sp = spec_b2[t], st = spat_b2[t];
        for (int c = 0; c < 128; c++) {
            sp += h1[c] * spec_w2[c * 80 + t];
            st += h2[c] * spat_w2[c * 80 + t];
        }
        float gz = gate_b[t], uz = unc_b[t];
        for (int c = 0; c < 256; c++) {
            gz += a_s[c] * gate_w[c * 80 + t];
            uz += a_s[c] * unc_w[c * 80 + t];
        }
        float g = 1.f / (1.f + expf(-gz));
        alph[t] = log1pf(expf(uz)) + 1.f;
        out[b * 80 + t] = g * sp + (1.f - g) * st;
        out[640 + b * 80 + t] = sp;
        out[1280 + b * 80 + t] = st;
        out[1920 + b * 80 + t] = g;
    }
    __syncthreads();
    if (t == 0) {
        float s = 0.f;
        for (int l = 0; l < 80; l++) s += alph[l];
        out[2560 + b] = 80.f / s;
    }
}

// ---------------- launcher ----------------
extern "C" void kernel_launch(void* const* d_in, const int* in_sizes, int n_in,
                              void* d_out, int out_size, void* d_ws, size_t ws_size,
                              hipStream_t stream)
{
    (void)in_sizes; (void)n_in; (void)out_size; (void)ws_size;
    const float* c2 = (const float*)d_in[0];
    const float* c3 = (const float*)d_in[1];
    const float* c4 = (const float*)d_in[2];
    const float* c5 = (const float*)d_in[3];
    const float* lat_w0 = (const float*)d_in[4];
    const float* lat_b0 = (const float*)d_in[5];
    const float* lat_w1 = (const float*)d_in[6];
    const float* lat_b1 = (const float*)d_in[7];
    const float* lat_w2 = (const float*)d_in[8];
    const float* lat_b2 = (const float*)d_in[9];
    const float* lat_w3 = (const float*)d_in[10];
    const float* lat_b3 = (const float*)d_in[11];
    const float* sp_w1 = (const float*)d_in[12];
    const float* sp_b1 = (const float*)d_in[13];
    const float* sp_w2 = (const float*)d_in[14];
    const float* sp_b2 = (const float*)d_in[15];
    const float* qkv_w = (const float*)d_in[16];
    const float* qkv_b = (const float*)d_in[17];
    const float* proj_w = (const float*)d_in[18];
    const float* proj_b = (const float*)d_in[19];
    const float* gat_W = (const float*)d_in[20];
    const float* gat_a = (const float*)d_in[21];
    const float* out_w = (const float*)d_in[22];
    const float* out_b = (const float*)d_in[23];
    const float* label_emb = (const float*)d_in[24];
    const float* spec_w1 = (const float*)d_in[25];
    const float* spec_b1 = (const float*)d_in[26];
    const float* spec_w2 = (const float*)d_in[27];
    const float* spec_b2 = (const float*)d_in[28];
    const float* spat_w1 = (const float*)d_in[29];
    const float* spat_b1 = (const float*)d_in[30];
    const float* spat_w2 = (const float*)d_in[31];
    const float* spat_b2 = (const float*)d_in[32];
    const float* gate_w = (const float*)d_in[33];
    const float* gate_b = (const float*)d_in[34];
    const float* unc_w = (const float*)d_in[35];
    const float* unc_b = (const float*)d_in[36];

    float* out = (float*)d_out;
    float* ws = (float*)d_ws;

    // workspace layout (floats); later phases reuse dead regions
    float* pf0    = ws + 0;        // 401408
    float* pf1    = ws + 401408;   // 802816
    float* pf2    = ws + 1204224;  // 1605632
    float* pf3    = ws + 2809856;  // 3211264
    float* pooled = ws + 6021120;  // 16384   (overlaps later 'graph' region - dead by then)
    float* beff   = ws + 6037504;  // 2048
    float* qkv    = ws + 0;        // reuses pf0/pf1
    float* S      = ws + 1204224;  // reuses pf2/pf3
    float* xo     = ws + 3662848;  // 401408
    float* proj   = ws + 4064256;  // 401408
    float* lf     = ws + 4465664;  // 163840
    float* Wx     = ws + 4629504;  // 655360
    float* concat = ws + 5284864;  // 655360
    float* graph  = ws + 5940224;  // 163840
    float* aggp   = ws + 6104064;  // 2048
    float* xtok   = ws + 6106112;  // 401408
    float* swpart = ws + 6106112;  // 32768 (reuses xtok region; dead before xtok_init)

    float* swp  = out + 2568;  // sw [8,4] (output 5)
    float* atts = out + 2600;  // atts [4,8,80,80] (output 6)

    // 1. pool features of all scales to 14x14 (+ c5 global mean)
    pool_scale<112><<<2048, 256, 0, stream>>>(c2, pf0, nullptr, 256);
    pool_scale<56><<<4096, 256, 0, stream>>>(c3, pf1, nullptr, 512);
    pool_scale<28><<<8192, 256, 0, stream>>>(c4, pf2, nullptr, 1024);
    pool_scale<14><<<16384, 256, 0, stream>>>(c5, pf3, pooled, 2048);
    // 2. scale weights + effective bias (split-K)
    sw_part<<<dim3(8, 8), 512, 0, stream>>>(pooled, sp_w1, swpart);
    sw_fin<<<8, 512, 0, stream>>>(swpart, sp_b1, sp_w2, sp_b2,
                                  lat_b0, lat_b1, lat_b2, lat_b3, swp, beff);
    // 3. lateral projection + sw combine -> x tokens [1568,256]
    xtok_init<<<1568, 256, 0, stream>>>(beff, xtok);
    lateral_slice<<<dim3(196, 8), 256, 0, stream>>>(pf0, pf1, pf2, pf3,
                                                    lat_w0, lat_w1, lat_w2, lat_w3,
                                                    swp, xtok);
    // 4. qkv = x @ qkv_w + qkv_b : [1568,768]
    gemm_kernel<true><<<dim3(49 * 12, 1, 1), 256, 0, stream>>>(
        xtok, 256, 0, 0, qkv_w, 768, 0, 0, qkv, 768, 0, 0,
        qkv_b, 1568, 768, 256, 1.f, 49);
    // 5. S = q @ k^T * hd^-0.5, per (b,h) : [64,196,196]
    gemm_kernel<false><<<dim3(7 * 4, 8, 8), 256, 0, stream>>>(
        qkv, 768, 150528, 32, qkv + 256, 768, 150528, 32,
        S, 196, 307328, 38416, nullptr, 196, 196, 32, 0.17677669529663687f, 7);
    // 6. row softmax on S (in place)
    attn_softmax<<<3136, 256, 0, stream>>>(S);
    // 7. xo = P @ v : [1568,256] (head-concat layout)
    gemm_kernel<true><<<dim3(7, 8, 8), 256, 0, stream>>>(
        S, 196, 307328, 38416, qkv + 512, 768, 150528, 32,
        xo, 256, 50176, 32, nullptr, 196, 32, 196, 1.f, 7);
    // 8. proj
    gemm_kernel<true><<<dim3(49 * 4, 1, 1), 256, 0, stream>>>(
        xo, 256, 0, 0, proj_w, 256, 0, 0, proj, 256, 0, 0,
        proj_b, 1568, 256, 256, 1.f, 49);
    // 9. gctx + lf
    projpost_kernel<<<8, 256, 0, stream>>>(proj, label_emb, lf);
    // 10. Wx[h] = lf @ gat_W[h] : [4,640,256]
    gemm_kernel<true><<<dim3(20 * 4, 1, 4), 256, 0, stream>>>(
        lf, 256, 0, 0, gat_W, 256, 0, 65536, Wx, 256, 0, 163840,
        nullptr, 640, 256, 256, 1.f, 20);
    // 11. GAT attention -> atts (output 6)
    gat_scores<<<dim3(8, 4), 256, 0, stream>>>(Wx, gat_a, atts);
    // 12. heads = atts @ Wx, written directly in concat layout [640,1024]
    gemm_kernel<true><<<dim3(3 * 4, 8, 4), 256, 0, stream>>>(
        atts, 80, 6400, 51200, Wx, 256, 20480, 163840,
        concat, 1024, 81920, 256, nullptr, 80, 256, 80, 1.f, 3);
    // 13. graph = concat @ out_w + out_b
    gemm_kernel<true><<<dim3(20 * 4, 1, 1), 256, 0, stream>>>(
        concat, 1024, 0, 0, out_w, 256, 0, 0, graph, 256, 0, 0,
        out_b, 640, 256, 1024, 1.f, 20);
    // 14. agg = label-mean
    agg_kernel<<<8, 256, 0, stream>>>(graph, aggp);
    // 15. final heads -> outputs 0..4
    final_kernel<<<8, 256, 0, stream>>>(aggp,
        spec_w1, spec_b1, spec_w2, spec_b2,
        spat_w1, spat_b1, spat_w2, spat_b2,
        gate_w, gate_b, unc_w, unc_b, out);
}

// Round 3
// 656.517 us; speedup vs baseline: 1.7273x; 1.3021x over previous
//
#include <hip/hip_runtime.h>
#include <math.h>

typedef __attribute__((ext_vector_type(8))) short bshort8;
typedef __attribute__((ext_vector_type(4))) float f32x4;

#define DI __device__ __forceinline__

DI unsigned short f2bf(float x) {
    unsigned int u = __builtin_bit_cast(unsigned int, x);
    u += 0x7fffu + ((u >> 16) & 1u);
    return (unsigned short)(u >> 16);
}

DI f32x4 mfma16(bshort8 a, bshort8 b, f32x4 c) {
    return __builtin_amdgcn_mfma_f32_16x16x32_bf16(a, b, c, 0, 0, 0);
}

// ---- composite (bilinear resize N->112, align_corners=False) + 8x8 avgpool stencils ----
// Derived in closed form from the reference op; boundary rows clamped. Zero-padded taps.
__device__ const float W14[14][3] = {
    {0.875f, 0.125f, 0.f},
    {0.125f, 0.75f, 0.125f}, {0.125f, 0.75f, 0.125f}, {0.125f, 0.75f, 0.125f},
    {0.125f, 0.75f, 0.125f}, {0.125f, 0.75f, 0.125f}, {0.125f, 0.75f, 0.125f},
    {0.125f, 0.75f, 0.125f}, {0.125f, 0.75f, 0.125f}, {0.125f, 0.75f, 0.125f},
    {0.125f, 0.75f, 0.125f}, {0.125f, 0.75f, 0.125f}, {0.125f, 0.75f, 0.125f},
    {0.125f, 0.875f, 0.f}};
__device__ const float W28[14][4] = {
    {0.5f, 0.4375f, 0.0625f, 0.f},
    {0.0625f, 0.4375f, 0.4375f, 0.0625f}, {0.0625f, 0.4375f, 0.4375f, 0.0625f},
    {0.0625f, 0.4375f, 0.4375f, 0.0625f}, {0.0625f, 0.4375f, 0.4375f, 0.0625f},
    {0.0625f, 0.4375f, 0.4375f, 0.0625f}, {0.0625f, 0.4375f, 0.4375f, 0.0625f},
    {0.0625f, 0.4375f, 0.4375f, 0.0625f}, {0.0625f, 0.4375f, 0.4375f, 0.0625f},
    {0.0625f, 0.4375f, 0.4375f, 0.0625f}, {0.0625f, 0.4375f, 0.4375f, 0.0625f},
    {0.0625f, 0.4375f, 0.4375f, 0.0625f}, {0.0625f, 0.4375f, 0.4375f, 0.0625f},
    {0.0625f, 0.4375f, 0.5f, 0.f}};
__device__ const float W56[14][6] = {
    {0.25f, 0.25f, 0.25f, 0.21875f, 0.03125f, 0.f},
    {0.03125f, 0.21875f, 0.25f, 0.25f, 0.21875f, 0.03125f},
    {0.03125f, 0.21875f, 0.25f, 0.25f, 0.21875f, 0.03125f},
    {0.03125f, 0.21875f, 0.25f, 0.25f, 0.21875f, 0.03125f},
    {0.03125f, 0.21875f, 0.25f, 0.25f, 0.21875f, 0.03125f},
    {0.03125f, 0.21875f, 0.25f, 0.25f, 0.21875f, 0.03125f},
    {0.03125f, 0.21875f, 0.25f, 0.25f, 0.21875f, 0.03125f},
    {0.03125f, 0.21875f, 0.25f, 0.25f, 0.21875f, 0.03125f},
    {0.03125f, 0.21875f, 0.25f, 0.25f, 0.21875f, 0.03125f},
    {0.03125f, 0.21875f, 0.25f, 0.25f, 0.21875f, 0.03125f},
    {0.03125f, 0.21875f, 0.25f, 0.25f, 0.21875f, 0.03125f},
    {0.03125f, 0.21875f, 0.25f, 0.25f, 0.21875f, 0.03125f},
    {0.03125f, 0.21875f, 0.25f, 0.25f, 0.21875f, 0.03125f},
    {0.03125f, 0.21875f, 0.25f, 0.25f, 0.25f, 0.f}};

// -------- K1: one thread per pooled output; pf layout [cin][1568], col = b*196 + r --------
template <int N, int C, int TAPS>
__global__ __launch_bounds__(256) void pool_elem(
    const float* __restrict__ src, float* __restrict__ dst)
{
    unsigned id = blockIdx.x * 256u + threadIdx.x;
    unsigned p = id / 196u;
    unsigned r = id - p * 196u;
    unsigned ti = r / 14u, tj = r - ti * 14u;
    unsigned b = p / C, cin = p - b * C;    // C is pow2
    const float* plane = src + (size_t)p * (N * N);
    float acc = 0.f;
    if constexpr (N == 112) {
        const float4* p4 = (const float4*)(plane + (size_t)(ti * 8) * 112 + tj * 8);
        #pragma unroll
        for (int i = 0; i < 8; i++) {
            float4 u = p4[i * 28];
            float4 v = p4[i * 28 + 1];
            acc += (u.x + u.y) + (u.z + u.w) + (v.x + v.y) + (v.z + v.w);
        }
        acc *= (1.f / 64.f);
    } else {
        constexpr int STRIDE = N / 14;
        const float (*WT)[TAPS] = (N == 14) ? (const float (*)[TAPS])W14
                                : (N == 28) ? (const float (*)[TAPS])W28
                                            : (const float (*)[TAPS])W56;
        int hs = (int)(STRIDE * ti) - 1; if (hs < 0) hs = 0;
        int ws = (int)(STRIDE * tj) - 1; if (ws < 0) ws = 0;
        float wh[TAPS], ww[TAPS];
        #pragma unroll
        for (int i = 0; i < TAPS; i++) { wh[i] = WT[ti][i]; ww[i] = WT[tj][i]; }
        #pragma unroll
        for (int i = 0; i < TAPS; i++) {
            int hi = hs + i; if (hi > N - 1) hi = N - 1;   // zero-weight tap; clamp for safety
            const float* row = plane + (size_t)hi * N;
            float rs = 0.f;
            #pragma unroll
            for (int j = 0; j < TAPS; j++) {
                int wj = ws + j; if (wj > N - 1) wj = N - 1;
                rs += ww[j] * row[wj];
            }
            acc += wh[i] * rs;
        }
    }
    dst[(size_t)cin * 1568 + b * 196 + r] = acc;
}

// -------- K1b: c5 global mean, one wave per plane --------
__global__ __launch_bounds__(256) void c5_mean(
    const float* __restrict__ c5, float* __restrict__ pooled)
{
    int wid = threadIdx.x >> 6, lane = threadIdx.x & 63;
    int p = blockIdx.x * 4 + wid;
    const float* plane = c5 + (size_t)p * 196;
    float v = plane[lane] + plane[64 + lane] + plane[128 + lane];
    if (lane < 4) v += plane[192 + lane];
    #pragma unroll
    for (int off = 32; off > 0; off >>= 1) v += __shfl_xor(v, off, 64);
    if (lane == 0) pooled[p] = v * (1.f / 196.f);
}

// -------- K2a: partial GEMV for scale-weight MLP layer 1 (split-K) --------
__global__ __launch_bounds__(512) void sw_part(
    const float* __restrict__ pooled, const float* __restrict__ sp_w1,
    float* __restrict__ partial)
{
    int b = blockIdx.x, kc = blockIdx.y, t = threadIdx.x;
    __shared__ float ps[256];
    if (t < 256) ps[t] = pooled[b * 2048 + kc * 256 + t];
    __syncthreads();
    float acc = 0.f;
    const float* w = sp_w1 + (size_t)(kc * 256) * 512 + t;
    #pragma unroll 4
    for (int c = 0; c < 256; c++) acc += ps[c] * w[(size_t)c * 512];
    partial[((size_t)b * 8 + kc) * 512 + t] = acc;
}

// -------- K2b: finish sw MLP --------
__global__ __launch_bounds__(512) void sw_fin(
    const float* __restrict__ partial, const float* __restrict__ sp_b1,
    const float* __restrict__ sp_w2, const float* __restrict__ sp_b2,
    const float* __restrict__ lb0, const float* __restrict__ lb1,
    const float* __restrict__ lb2, const float* __restrict__ lb3,
    float* __restrict__ sw_out, float* __restrict__ beff)
{
    int b = blockIdx.x, t = threadIdx.x;
    __shared__ float h[512];
    __shared__ float s4s[4];
    __shared__ float swl[4];
    float a = sp_b1[t];
    #pragma unroll
    for (int kc = 0; kc < 8; kc++) a += partial[((size_t)b * 8 + kc) * 512 + t];
    h[t] = fmaxf(a, 0.f);
    __syncthreads();
    int wv = t >> 6, lane = t & 63;
    if (wv < 4) {
        float acc = 0.f;
        #pragma unroll
        for (int i = 0; i < 8; i++) {
            int idx = lane + 64 * i;
            acc += h[idx] * sp_w2[idx * 4 + wv];
        }
        #pragma unroll
        for (int off = 32; off > 0; off >>= 1) acc += __shfl_xor(acc, off, 64);
        if (lane == 0) s4s[wv] = acc + sp_b2[wv];
    }
    __syncthreads();
    if (t == 0) {
        float mx = fmaxf(fmaxf(s4s[0], s4s[1]), fmaxf(s4s[2], s4s[3]));
        float e0 = expf(s4s[0] - mx), e1 = expf(s4s[1] - mx);
        float e2 = expf(s4s[2] - mx), e3 = expf(s4s[3] - mx);
        float inv = 1.f / (e0 + e1 + e2 + e3);
        swl[0] = e0 * inv; swl[1] = e1 * inv; swl[2] = e2 * inv; swl[3] = e3 * inv;
        for (int o = 0; o < 4; o++) sw_out[b * 4 + o] = swl[o];
    }
    __syncthreads();
    if (t < 256)
        beff[b * 256 + t] = swl[0] * lb0[t] + swl[1] * lb1[t] + swl[2] * lb2[t] + swl[3] * lb3[t];
}

// -------- K3a: init xtok with effective bias --------
__global__ __launch_bounds__(256) void xtok_init(
    const float* __restrict__ beff, float* __restrict__ xtok)
{
    int m = blockIdx.x, c = threadIdx.x;
    xtok[(size_t)m * 256 + c] = beff[(m / 196) * 256 + c];
}

// -------- K3b: lateral projection, K split into 8 slices, atomic accumulate --------
__global__ __launch_bounds__(256) void lateral_slice(
    const float* __restrict__ pf0, const float* __restrict__ pf1,
    const float* __restrict__ pf2, const float* __restrict__ pf3,
    const float* __restrict__ w0, const float* __restrict__ w1,
    const float* __restrict__ w2, const float* __restrict__ w3,
    const float* __restrict__ sw, float* __restrict__ xtok)
{
    const int sArr[8]   = {0, 1, 2, 2, 3, 3, 3, 3};
    const int koffArr[8] = {0, 0, 0, 512, 0, 512, 1024, 1536};
    const int klenArr[8] = {256, 512, 512, 512, 512, 512, 512, 512};
    int sl = blockIdx.y;
    int s = sArr[sl], koff = koffArr[sl], klen = klenArr[sl];
    const float* pf = (s == 0) ? pf0 : (s == 1) ? pf1 : (s == 2) ? pf2 : pf3;
    const float* W  = (s == 0) ? w0  : (s == 1) ? w1  : (s == 2) ? w2  : w3;

    int mt = blockIdx.x % 49, nt = blockIdx.x / 49;
    int m0 = mt * 32, n0 = nt * 64;
    __shared__ alignas(16) unsigned short As[1024];
    __shared__ alignas(16) unsigned short Bs[2048];
    int t = threadIdx.x, lane = t & 63, wid = t >> 6;
    int wm = wid >> 1, wn = wid & 1;
    f32x4 acc0 = {0, 0, 0, 0}, acc1 = {0, 0, 0, 0};

    int m_l = t % 32;
    int kqA = t / 32;
    int bb = (m0 + m_l) / 196;
    int k_lB = t / 8;
    int c8B = t % 8;
    float swv = sw[bb * 4 + s];

    for (int k0 = 0; k0 < klen; k0 += 32) {
        #pragma unroll
        for (int i = 0; i < 4; i++) {
            int k_l = kqA * 4 + i;
            float v = pf[(size_t)(koff + k0 + k_l) * 1568 + m0 + m_l] * swv;
            As[(m_l >> 4) * 512 + ((m_l & 15) + ((k_l >> 3) << 4)) * 8 + (k_l & 7)] = f2bf(v);
        }
        #pragma unroll
        for (int i = 0; i < 8; i++) {
            int n_l = c8B * 8 + i;
            float v = W[(size_t)(koff + k0 + k_lB) * 256 + n0 + n_l];
            Bs[(n_l >> 4) * 512 + ((n_l & 15) + ((k_lB >> 3) << 4)) * 8 + (k_lB & 7)] = f2bf(v);
        }
        __syncthreads();
        bshort8 av = *(const bshort8*)&As[wm * 512 + lane * 8];
        bshort8 bv0 = *(const bshort8*)&Bs[(wn * 2 + 0) * 512 + lane * 8];
        bshort8 bv1 = *(const bshort8*)&Bs[(wn * 2 + 1) * 512 + lane * 8];
        acc0 = mfma16(av, bv0, acc0);
        acc1 = mfma16(av, bv1, acc1);
        __syncthreads();
    }
    int col0 = n0 + wn * 32 + (lane & 15);
    int rbase = m0 + wm * 16 + ((lane >> 4) << 2);
    #pragma unroll
    for (int r = 0; r < 4; r++) {
        int m = rbase + r;
        atomicAdd(&xtok[(size_t)m * 256 + col0], acc0[r]);
        atomicAdd(&xtok[(size_t)m * 256 + col0 + 16], acc1[r]);
    }
}

// -------- generic bf16-MFMA GEMM --------
template <bool B_IS_KXN>
__global__ __launch_bounds__(256) void gemm_kernel(
    const float* __restrict__ Ab, int lda, long long sAy, long long sAz,
    const float* __restrict__ Bb, int ldb, long long sBy, long long sBz,
    float* __restrict__ Cb, int ldc, long long sCy, long long sCz,
    const float* __restrict__ bias, int M, int N, int K,
    float alpha, int mtiles)
{
    const float* A = Ab + blockIdx.y * sAy + blockIdx.z * sAz;
    const float* B = Bb + blockIdx.y * sBy + blockIdx.z * sBz;
    float* C = Cb + blockIdx.y * sCy + blockIdx.z * sCz;
    int mt = blockIdx.x % mtiles, nt = blockIdx.x / mtiles;
    int m0 = mt * 32, n0 = nt * 64;
    __shared__ alignas(16) unsigned short As[1024];
    __shared__ alignas(16) unsigned short Bs[2048];
    int t = threadIdx.x, lane = t & 63, wid = t >> 6;
    int wm = wid >> 1, wn = wid & 1;
    f32x4 acc0 = {0, 0, 0, 0}, acc1 = {0, 0, 0, 0};

    for (int k0 = 0; k0 < K; k0 += 32) {
        {
            int m_l = t / 8, kq = t % 8;
            int m = m0 + m_l;
            #pragma unroll
            for (int i = 0; i < 4; i++) {
                int k_l = kq * 4 + i;
                int k = k0 + k_l;
                float v = (m < M && k < K) ? A[(size_t)m * lda + k] : 0.f;
                As[(m_l >> 4) * 512 + ((m_l & 15) + ((k_l >> 3) << 4)) * 8 + (k_l & 7)] = f2bf(v);
            }
        }
        if constexpr (B_IS_KXN) {
            int k_l = t / 8, c8 = t % 8;
            int k = k0 + k_l;
            #pragma unroll
            for (int i = 0; i < 8; i++) {
                int n_l = c8 * 8 + i;
                int n = n0 + n_l;
                float v = (k < K && n < N) ? B[(size_t)k * ldb + n] : 0.f;
                Bs[(n_l >> 4) * 512 + ((n_l & 15) + ((k_l >> 3) << 4)) * 8 + (k_l & 7)] = f2bf(v);
            }
        } else {
            #pragma unroll
            for (int g = 0; g < 2; g++) {
                int n_l = (t / 8) + 32 * g;
                int kq = t % 8;
                int n = n0 + n_l;
                #pragma unroll
                for (int i = 0; i < 4; i++) {
                    int k_l = kq * 4 + i;
                    int k = k0 + k_l;
                    float v = (n < N && k < K) ? B[(size_t)n * ldb + k] : 0.f;
                    Bs[(n_l >> 4) * 512 + ((n_l & 15) + ((k_l >> 3) << 4)) * 8 + (k_l & 7)] = f2bf(v);
                }
            }
        }
        __syncthreads();
        bshort8 av = *(const bshort8*)&As[wm * 512 + lane * 8];
        bshort8 bv0 = *(const bshort8*)&Bs[(wn * 2 + 0) * 512 + lane * 8];
        bshort8 bv1 = *(const bshort8*)&Bs[(wn * 2 + 1) * 512 + lane * 8];
        acc0 = mfma16(av, bv0, acc0);
        acc1 = mfma16(av, bv1, acc1);
        __syncthreads();
    }
    int col0 = n0 + wn * 32 + (lane & 15);
    int rbase = m0 + wm * 16 + ((lane >> 4) << 2);
    #pragma unroll
    for (int r = 0; r < 4; r++) {
        int m = rbase + r;
        if (m < M) {
            if (col0 < N) {
                float v = acc0[r] * alpha;
                if (bias) v += bias[col0];
                C[(size_t)m * ldc + col0] = v;
            }
            int c1 = col0 + 16;
            if (c1 < N) {
                float v = acc1[r] * alpha;
                if (bias) v += bias[c1];
                C[(size_t)m * ldc + c1] = v;
            }
        }
    }
}

// -------- attention softmax over rows of S [12544][196], in place --------
__global__ __launch_bounds__(256) void attn_softmax(float* __restrict__ S)
{
    int wid = threadIdx.x >> 6, lane = threadIdx.x & 63;
    size_t row = (size_t)blockIdx.x * 4 + wid;
    float* p = S + row * 196;
    float v0 = p[lane];
    float v1 = p[64 + lane];
    float v2 = p[128 + lane];
    float v3 = (lane < 4) ? p[192 + lane] : -1e30f;
    float mx = fmaxf(fmaxf(v0, v1), fmaxf(v2, v3));
    #pragma unroll
    for (int off = 32; off > 0; off >>= 1) mx = fmaxf(mx, __shfl_xor(mx, off, 64));
    float e0 = expf(v0 - mx), e1 = expf(v1 - mx), e2 = expf(v2 - mx);
    float e3 = (lane < 4) ? expf(v3 - mx) : 0.f;
    float sum = e0 + e1 + e2 + e3;
    #pragma unroll
    for (int off = 32; off > 0; off >>= 1) sum += __shfl_xor(sum, off, 64);
    float inv = 1.f / sum;
    p[lane] = e0 * inv;
    p[64 + lane] = e1 * inv;
    p[128 + lane] = e2 * inv;
    if (lane < 4) p[192 + lane] = e3 * inv;
}

// -------- post-proj: gctx = token-mean; lf = label_emb + gctx --------
__global__ __launch_bounds__(256) void projpost_kernel(
    const float* __restrict__ proj, const float* __restrict__ lemb, float* __restrict__ lf)
{
    int b = blockIdx.x, c = threadIdx.x;
    float sum = 0.f;
    for (int n = 0; n < 196; n++) sum += proj[((size_t)b * 196 + n) * 256 + c];
    float g = sum / 196.f;
    for (int l = 0; l < 80; l++)
        lf[((size_t)b * 80 + l) * 256 + c] = lemb[l * 256 + c] + g;
}

// -------- GAT attention scores -> atts (output 6) --------
__global__ __launch_bounds__(256) void gat_scores(
    const float* __restrict__ Wx, const float* __restrict__ gat_a, float* __restrict__ atts)
{
    int b = blockIdx.x, h = blockIdx.y, t = threadIdx.x;
    __shared__ float s1[80], s2[80];
    if (t < 160) {
        int which = t / 80, l = t % 80;
        const float* row = Wx + ((size_t)h * 640 + b * 80 + l) * 256;
        const float* av = gat_a + h * 512 + which * 256;
        float acc = 0.f;
        for (int c = 0; c < 256; c++) acc += row[c] * av[c];
        if (which) s2[l] = acc; else s1[l] = acc;
    }
    __syncthreads();
    if (t < 80) {
        float si = s1[t];
        float mx = -1e30f;
        for (int j = 0; j < 80; j++) {
            float v = si + s2[j];
            v = v > 0.f ? v : 0.2f * v;
            mx = fmaxf(mx, v);
        }
        float sum = 0.f;
        for (int j = 0; j < 80; j++) {
            float v = si + s2[j];
            v = v > 0.f ? v : 0.2f * v;
            sum += expf(v - mx);
        }
        float inv = 1.f / sum;
        float* orow = atts + (size_t)h * 51200 + b * 6400 + t * 80;
        for (int j = 0; j < 80; j++) {
            float v = si + s2[j];
            v = v > 0.f ? v : 0.2f * v;
            orow[j] = expf(v - mx) * inv;
        }
    }
}

// -------- agg = mean over labels --------
__global__ __launch_bounds__(256) void agg_kernel(const float* __restrict__ graph, float* __restrict__ agg)
{
    int b = blockIdx.x, c = threadIdx.x;
    float sum = 0.f;
    for (int l = 0; l < 80; l++) sum += graph[((size_t)b * 80 + l) * 256 + c];
    agg[b * 256 + c] = sum / 80.f;
}

// -------- final heads --------
__global__ __launch_bounds__(256) void final_kernel(
    const float* __restrict__ agg,
    const float* __restrict__ spec_w1, const float* __restrict__ spec_b1,
    const float* __restrict__ spec_w2, const float* __restrict__ spec_b2,
    const float* __restrict__ spat_w1, const float* __restrict__ spat_b1,
    const float* __restrict__ spat_w2, const float* __restrict__ spat_b2,
    const float* __restrict__ gate_w, const float* __restrict__ gate_b,
    const float* __restrict__ unc_w, const float* __restrict__ unc_b,
    float* __restrict__ out)
{
    int b = blockIdx.x, t = threadIdx.x;
    __shared__ float a_s[256], h1[128], h2[128], alph[80];
    a_s[t] = agg[b * 256 + t];
    __syncthreads();
    if (t < 128) {
        float acc1 = spec_b1[t], acc2 = spat_b1[t];
        for (int c = 0; c < 256; c++) {
            acc1 += a_s[c] * spec_w1[c * 128 + t];
            acc2 += a_s[c] * spat_w1[c * 128 + t];
        }
        h1[t] = fmaxf(acc1, 0.f);
        h2[t] = fmaxf(acc2, 0.f);
    }
    __syncthreads();
    if (t < 80) {
        float sp = spec_b2[t], st = spat_b2[t];
        for (int c = 0; c < 128; c++) {
            sp += h1[c] * spec_w2[c * 80 + t];
            st += h2[c] * spat_w2[c * 80 + t];
        }
        float gz = gate_b[t], uz = unc_b[t];
        for (int c = 0; c < 256; c++) {
            gz += a_s[c] * gate_w[c * 80 + t];
            uz += a_s[c] * unc_w[c * 80 + t];
        }
        float g = 1.f / (1.f + expf(-gz));
        alph[t] = log1pf(expf(uz)) + 1.f;
        out[b * 80 + t] = g * sp + (1.f - g) * st;
        out[640 + b * 80 + t] = sp;
        out[1280 + b * 80 + t] = st;
        out[1920 + b * 80 + t] = g;
    }
    __syncthreads();
    if (t == 0) {
        float s = 0.f;
        for (int l = 0; l < 80; l++) s += alph[l];
        out[2560 + b] = 80.f / s;
    }
}

// ---------------- launcher ----------------
extern "C" void kernel_launch(void* const* d_in, const int* in_sizes, int n_in,
                              void* d_out, int out_size, void* d_ws, size_t ws_size,
                              hipStream_t stream)
{
    (void)in_sizes; (void)n_in; (void)out_size; (void)ws_size;
    const float* c2 = (const float*)d_in[0];
    const float* c3 = (const float*)d_in[1];
    const float* c4 = (const float*)d_in[2];
    const float* c5 = (const float*)d_in[3];
    const float* lat_w0 = (const float*)d_in[4];
    const float* lat_b0 = (const float*)d_in[5];
    const float* lat_w1 = (const float*)d_in[6];
    const float* lat_b1 = (const float*)d_in[7];
    const float* lat_w2 = (const float*)d_in[8];
    const float* lat_b2 = (const float*)d_in[9];
    const float* lat_w3 = (const float*)d_in[10];
    const float* lat_b3 = (const float*)d_in[11];
    const float* sp_w1 = (const float*)d_in[12];
    const float* sp_b1 = (const float*)d_in[13];
    const float* sp_w2 = (const float*)d_in[14];
    const float* sp_b2 = (const float*)d_in[15];
    const float* qkv_w = (const float*)d_in[16];
    const float* qkv_b = (const float*)d_in[17];
    const float* proj_w = (const float*)d_in[18];
    const float* proj_b = (const float*)d_in[19];
    const float* gat_W = (const float*)d_in[20];
    const float* gat_a = (const float*)d_in[21];
    const float* out_w = (const float*)d_in[22];
    const float* out_b = (const float*)d_in[23];
    const float* label_emb = (const float*)d_in[24];
    const float* spec_w1 = (const float*)d_in[25];
    const float* spec_b1 = (const float*)d_in[26];
    const float* spec_w2 = (const float*)d_in[27];
    const float* spec_b2 = (const float*)d_in[28];
    const float* spat_w1 = (const float*)d_in[29];
    const float* spat_b1 = (const float*)d_in[30];
    const float* spat_w2 = (const float*)d_in[31];
    const float* spat_b2 = (const float*)d_in[32];
    const float* gate_w = (const float*)d_in[33];
    const float* gate_b = (const float*)d_in[34];
    const float* unc_w = (const float*)d_in[35];
    const float* unc_b = (const float*)d_in[36];

    float* out = (float*)d_out;
    float* ws = (float*)d_ws;

    // workspace layout (floats); later phases reuse dead regions
    float* pf0    = ws + 0;        // 401408
    float* pf1    = ws + 401408;   // 802816
    float* pf2    = ws + 1204224;  // 1605632
    float* pf3    = ws + 2809856;  // 3211264
    float* pooled = ws + 6021120;  // 16384
    float* beff   = ws + 6037504;  // 2048
    float* qkv    = ws + 0;        // reuses pf0/pf1
    float* S      = ws + 1204224;  // reuses pf2/pf3
    float* xo     = ws + 3662848;  // 401408
    float* proj   = ws + 4064256;  // 401408
    float* lf     = ws + 4465664;  // 163840
    float* Wx     = ws + 4629504;  // 655360
    float* concat = ws + 5284864;  // 655360
    float* graph  = ws + 5940224;  // 163840
    float* aggp   = ws + 6104064;  // 2048
    float* xtok   = ws + 6106112;  // 401408
    float* swpart = ws + 6106112;  // 32768 (reuses xtok region; dead before xtok_init)

    float* swp  = out + 2568;  // sw [8,4] (output 5)
    float* atts = out + 2600;  // atts [4,8,80,80] (output 6)

    // 1. pool features of all scales to 14x14 (+ c5 global mean)
    pool_elem<112, 256, 8><<<1568, 256, 0, stream>>>(c2, pf0);
    pool_elem<56, 512, 6><<<3136, 256, 0, stream>>>(c3, pf1);
    pool_elem<28, 1024, 4><<<6272, 256, 0, stream>>>(c4, pf2);
    pool_elem<14, 2048, 3><<<12544, 256, 0, stream>>>(c5, pf3);
    c5_mean<<<4096, 256, 0, stream>>>(c5, pooled);
    // 2. scale weights + effective bias (split-K)
    sw_part<<<dim3(8, 8), 512, 0, stream>>>(pooled, sp_w1, swpart);
    sw_fin<<<8, 512, 0, stream>>>(swpart, sp_b1, sp_w2, sp_b2,
                                  lat_b0, lat_b1, lat_b2, lat_b3, swp, beff);
    // 3. lateral projection + sw combine -> x tokens [1568,256]
    xtok_init<<<1568, 256, 0, stream>>>(beff, xtok);
    lateral_slice<<<dim3(196, 8), 256, 0, stream>>>(pf0, pf1, pf2, pf3,
                                                    lat_w0, lat_w1, lat_w2, lat_w3,
                                                    swp, xtok);
    // 4. qkv = x @ qkv_w + qkv_b : [1568,768]
    gemm_kernel<true><<<dim3(49 * 12, 1, 1), 256, 0, stream>>>(
        xtok, 256, 0, 0, qkv_w, 768, 0, 0, qkv, 768, 0, 0,
        qkv_b, 1568, 768, 256, 1.f, 49);
    // 5. S = q @ k^T * hd^-0.5, per (b,h) : [64,196,196]
    gemm_kernel<false><<<dim3(7 * 4, 8, 8), 256, 0, stream>>>(
        qkv, 768, 150528, 32, qkv + 256, 768, 150528, 32,
        S, 196, 307328, 38416, nullptr, 196, 196, 32, 0.17677669529663687f, 7);
    // 6. row softmax on S (in place)
    attn_softmax<<<3136, 256, 0, stream>>>(S);
    // 7. xo = P @ v : [1568,256] (head-concat layout)
    gemm_kernel<true><<<dim3(7, 8, 8), 256, 0, stream>>>(
        S, 196, 307328, 38416, qkv + 512, 768, 150528, 32,
        xo, 256, 50176, 32, nullptr, 196, 32, 196, 1.f, 7);
    // 8. proj
    gemm_kernel<true><<<dim3(49 * 4, 1, 1), 256, 0, stream>>>(
        xo, 256, 0, 0, proj_w, 256, 0, 0, proj, 256, 0, 0,
        proj_b, 1568, 256, 256, 1.f, 49);
    // 9. gctx + lf
    projpost_kernel<<<8, 256, 0, stream>>>(proj, label_emb, lf);
    // 10. Wx[h] = lf @ gat_W[h] : [4,640,256]
    gemm_kernel<true><<<dim3(20 * 4, 1, 4), 256, 0, stream>>>(
        lf, 256, 0, 0, gat_W, 256, 0, 65536, Wx, 256, 0, 163840,
        nullptr, 640, 256, 256, 1.f, 20);
    // 11. GAT attention -> atts (output 6)
    gat_scores<<<dim3(8, 4), 256, 0, stream>>>(Wx, gat_a, atts);
    // 12. heads = atts @ Wx, written directly in concat layout [640,1024]
    gemm_kernel<true><<<dim3(3 * 4, 8, 4), 256, 0, stream>>>(
        atts, 80, 6400, 51200, Wx, 256, 20480, 163840,
        concat, 1024, 81920, 256, nullptr, 80, 256, 80, 1.f, 3);
    // 13. graph = concat @ out_w + out_b
    gemm_kernel<true><<<dim3(20 * 4, 1, 1), 256, 0, stream>>>(
        concat, 1024, 0, 0, out_w, 256, 0, 0, graph, 256, 0, 0,
        out_b, 640, 256, 1024, 1.f, 20);
    // 14. agg = label-mean
    agg_kernel<<<8, 256, 0, stream>>>(graph, aggp);
    // 15. final heads -> outputs 0..4
    final_kernel<<<8, 256, 0, stream>>>(aggp,
        spec_w1, spec_b1, spec_w2, spec_b2,
        spat_w1, spat_b1, spat_w2, spat_b2,
        gate_w, gate_b, unc_w, unc_b, out);
}

// Round 4
// 598.185 us; speedup vs baseline: 1.8957x; 1.0975x over previous
//
#include <hip/hip_runtime.h>
#include <math.h>

typedef __attribute__((ext_vector_type(8))) short bshort8;
typedef __attribute__((ext_vector_type(4))) float f32x4;

#define DI __device__ __forceinline__

DI unsigned short f2bf(float x) {
    unsigned int u = __builtin_bit_cast(unsigned int, x);
    u += 0x7fffu + ((u >> 16) & 1u);
    return (unsigned short)(u >> 16);
}

DI bshort8 pack8(const float* v) {
    bshort8 r;
    #pragma unroll
    for (int j = 0; j < 8; j++) r[j] = (short)f2bf(v[j]);
    return r;
}

DI f32x4 mfma16(bshort8 a, bshort8 b, f32x4 c) {
    return __builtin_amdgcn_mfma_f32_16x16x32_bf16(a, b, c, 0, 0, 0);
}

// ---- composite (bilinear resize N->112, align_corners=False) + 8x8 avgpool stencils ----
__device__ const float W14[14][3] = {
    {0.875f, 0.125f, 0.f},
    {0.125f, 0.75f, 0.125f}, {0.125f, 0.75f, 0.125f}, {0.125f, 0.75f, 0.125f},
    {0.125f, 0.75f, 0.125f}, {0.125f, 0.75f, 0.125f}, {0.125f, 0.75f, 0.125f},
    {0.125f, 0.75f, 0.125f}, {0.125f, 0.75f, 0.125f}, {0.125f, 0.75f, 0.125f},
    {0.125f, 0.75f, 0.125f}, {0.125f, 0.75f, 0.125f}, {0.125f, 0.75f, 0.125f},
    {0.125f, 0.875f, 0.f}};
__device__ const float W28[14][4] = {
    {0.5f, 0.4375f, 0.0625f, 0.f},
    {0.0625f, 0.4375f, 0.4375f, 0.0625f}, {0.0625f, 0.4375f, 0.4375f, 0.0625f},
    {0.0625f, 0.4375f, 0.4375f, 0.0625f}, {0.0625f, 0.4375f, 0.4375f, 0.0625f},
    {0.0625f, 0.4375f, 0.4375f, 0.0625f}, {0.0625f, 0.4375f, 0.4375f, 0.0625f},
    {0.0625f, 0.4375f, 0.4375f, 0.0625f}, {0.0625f, 0.4375f, 0.4375f, 0.0625f},
    {0.0625f, 0.4375f, 0.4375f, 0.0625f}, {0.0625f, 0.4375f, 0.4375f, 0.0625f},
    {0.0625f, 0.4375f, 0.4375f, 0.0625f}, {0.0625f, 0.4375f, 0.4375f, 0.0625f},
    {0.0625f, 0.4375f, 0.5f, 0.f}};
__device__ const float W56[14][6] = {
    {0.25f, 0.25f, 0.25f, 0.21875f, 0.03125f, 0.f},
    {0.03125f, 0.21875f, 0.25f, 0.25f, 0.21875f, 0.03125f},
    {0.03125f, 0.21875f, 0.25f, 0.25f, 0.21875f, 0.03125f},
    {0.03125f, 0.21875f, 0.25f, 0.25f, 0.21875f, 0.03125f},
    {0.03125f, 0.21875f, 0.25f, 0.25f, 0.21875f, 0.03125f},
    {0.03125f, 0.21875f, 0.25f, 0.25f, 0.21875f, 0.03125f},
    {0.03125f, 0.21875f, 0.25f, 0.25f, 0.21875f, 0.03125f},
    {0.03125f, 0.21875f, 0.25f, 0.25f, 0.21875f, 0.03125f},
    {0.03125f, 0.21875f, 0.25f, 0.25f, 0.21875f, 0.03125f},
    {0.03125f, 0.21875f, 0.25f, 0.25f, 0.21875f, 0.03125f},
    {0.03125f, 0.21875f, 0.25f, 0.25f, 0.21875f, 0.03125f},
    {0.03125f, 0.21875f, 0.25f, 0.25f, 0.21875f, 0.03125f},
    {0.03125f, 0.21875f, 0.25f, 0.25f, 0.21875f, 0.03125f},
    {0.03125f, 0.21875f, 0.25f, 0.25f, 0.25f, 0.f}};

// -------- K1: one thread per pooled output; pf layout [cin][1568], col = b*196 + r --------
template <int N, int C, int TAPS>
__global__ __launch_bounds__(256) void pool_elem(
    const float* __restrict__ src, float* __restrict__ dst)
{
    unsigned id = blockIdx.x * 256u + threadIdx.x;
    unsigned p = id / 196u;
    unsigned r = id - p * 196u;
    unsigned ti = r / 14u, tj = r - ti * 14u;
    unsigned b = p / C, cin = p - b * C;
    const float* plane = src + (size_t)p * (N * N);
    float acc = 0.f;
    if constexpr (N == 112) {
        const float4* p4 = (const float4*)(plane + (size_t)(ti * 8) * 112 + tj * 8);
        #pragma unroll
        for (int i = 0; i < 8; i++) {
            float4 u = p4[i * 28];
            float4 v = p4[i * 28 + 1];
            acc += (u.x + u.y) + (u.z + u.w) + (v.x + v.y) + (v.z + v.w);
        }
        acc *= (1.f / 64.f);
    } else {
        constexpr int STRIDE = N / 14;
        const float (*WT)[TAPS] = (N == 14) ? (const float (*)[TAPS])W14
                                : (N == 28) ? (const float (*)[TAPS])W28
                                            : (const float (*)[TAPS])W56;
        int hs = (int)(STRIDE * ti) - 1; if (hs < 0) hs = 0;
        int ws = (int)(STRIDE * tj) - 1; if (ws < 0) ws = 0;
        float wh[TAPS], ww[TAPS];
        #pragma unroll
        for (int i = 0; i < TAPS; i++) { wh[i] = WT[ti][i]; ww[i] = WT[tj][i]; }
        #pragma unroll
        for (int i = 0; i < TAPS; i++) {
            int hi = hs + i; if (hi > N - 1) hi = N - 1;
            const float* row = plane + (size_t)hi * N;
            float rs = 0.f;
            #pragma unroll
            for (int j = 0; j < TAPS; j++) {
                int wj = ws + j; if (wj > N - 1) wj = N - 1;
                rs += ww[j] * row[wj];
            }
            acc += wh[i] * rs;
        }
    }
    dst[(size_t)cin * 1568 + b * 196 + r] = acc;
}

// -------- K1b: c5 global mean, one wave per plane --------
__global__ __launch_bounds__(256) void c5_mean(
    const float* __restrict__ c5, float* __restrict__ pooled)
{
    int wid = threadIdx.x >> 6, lane = threadIdx.x & 63;
    int p = blockIdx.x * 4 + wid;
    const float* plane = c5 + (size_t)p * 196;
    float v = plane[lane] + plane[64 + lane] + plane[128 + lane];
    if (lane < 4) v += plane[192 + lane];
    #pragma unroll
    for (int off = 32; off > 0; off >>= 1) v += __shfl_xor(v, off, 64);
    if (lane == 0) pooled[p] = v * (1.f / 196.f);
}

// -------- K2a: partial GEMV for scale-weight MLP layer 1 (split-K) --------
__global__ __launch_bounds__(512) void sw_part(
    const float* __restrict__ pooled, const float* __restrict__ sp_w1,
    float* __restrict__ partial)
{
    int b = blockIdx.x, kc = blockIdx.y, t = threadIdx.x;
    __shared__ float ps[256];
    if (t < 256) ps[t] = pooled[b * 2048 + kc * 256 + t];
    __syncthreads();
    float acc = 0.f;
    const float* w = sp_w1 + (size_t)(kc * 256) * 512 + t;
    #pragma unroll 4
    for (int c = 0; c < 256; c++) acc += ps[c] * w[(size_t)c * 512];
    partial[((size_t)b * 8 + kc) * 512 + t] = acc;
}

// -------- K2b: finish sw MLP --------
__global__ __launch_bounds__(512) void sw_fin(
    const float* __restrict__ partial, const float* __restrict__ sp_b1,
    const float* __restrict__ sp_w2, const float* __restrict__ sp_b2,
    const float* __restrict__ lb0, const float* __restrict__ lb1,
    const float* __restrict__ lb2, const float* __restrict__ lb3,
    float* __restrict__ sw_out, float* __restrict__ beff)
{
    int b = blockIdx.x, t = threadIdx.x;
    __shared__ float h[512];
    __shared__ float s4s[4];
    __shared__ float swl[4];
    float a = sp_b1[t];
    #pragma unroll
    for (int kc = 0; kc < 8; kc++) a += partial[((size_t)b * 8 + kc) * 512 + t];
    h[t] = fmaxf(a, 0.f);
    __syncthreads();
    int wv = t >> 6, lane = t & 63;
    if (wv < 4) {
        float acc = 0.f;
        #pragma unroll
        for (int i = 0; i < 8; i++) {
            int idx = lane + 64 * i;
            acc += h[idx] * sp_w2[idx * 4 + wv];
        }
        #pragma unroll
        for (int off = 32; off > 0; off >>= 1) acc += __shfl_xor(acc, off, 64);
        if (lane == 0) s4s[wv] = acc + sp_b2[wv];
    }
    __syncthreads();
    if (t == 0) {
        float mx = fmaxf(fmaxf(s4s[0], s4s[1]), fmaxf(s4s[2], s4s[3]));
        float e0 = expf(s4s[0] - mx), e1 = expf(s4s[1] - mx);
        float e2 = expf(s4s[2] - mx), e3 = expf(s4s[3] - mx);
        float inv = 1.f / (e0 + e1 + e2 + e3);
        swl[0] = e0 * inv; swl[1] = e1 * inv; swl[2] = e2 * inv; swl[3] = e3 * inv;
        for (int o = 0; o < 4; o++) sw_out[b * 4 + o] = swl[o];
    }
    __syncthreads();
    if (t < 256)
        beff[b * 256 + t] = swl[0] * lb0[t] + swl[1] * lb1[t] + swl[2] * lb2[t] + swl[3] * lb3[t];
}

// -------- K3a: init xtok with effective bias --------
__global__ __launch_bounds__(256) void xtok_init(
    const float* __restrict__ beff, float* __restrict__ xtok)
{
    int m = blockIdx.x, c = threadIdx.x;
    xtok[(size_t)m * 256 + c] = beff[(m / 196) * 256 + c];
}

// -------- K3b: lateral projection, fragment-direct staging, split into 8 K-slices --------
__global__ __launch_bounds__(256) void lateral_slice(
    const float* __restrict__ pf0, const float* __restrict__ pf1,
    const float* __restrict__ pf2, const float* __restrict__ pf3,
    const float* __restrict__ w0, const float* __restrict__ w1,
    const float* __restrict__ w2, const float* __restrict__ w3,
    const float* __restrict__ sw, float* __restrict__ xtok)
{
    const int sArr[8]    = {0, 1, 2, 2, 3, 3, 3, 3};
    const int koffArr[8] = {0, 0, 0, 512, 0, 512, 1024, 1536};
    const int klenArr[8] = {256, 512, 512, 512, 512, 512, 512, 512};
    int sl = blockIdx.y;
    int s = sArr[sl], koff = koffArr[sl], klen = klenArr[sl];
    const float* pf = (s == 0) ? pf0 : (s == 1) ? pf1 : (s == 2) ? pf2 : pf3;
    const float* W  = (s == 0) ? w0  : (s == 1) ? w1  : (s == 2) ? w2  : w3;

    int mt = blockIdx.x % 49, nt = blockIdx.x / 49;
    int m0 = mt * 32, n0 = nt * 64;
    __shared__ alignas(16) unsigned short As[1024];
    __shared__ alignas(16) unsigned short Bs[2048];
    int t = threadIdx.x, lane = t & 63, wid = t >> 6;
    int wm = wid >> 1, wn = wid & 1;
    f32x4 acc0 = {0, 0, 0, 0}, acc1 = {0, 0, 0, 0};

    int f = t & 63;
    int mA = m0 + ((t >> 6) & 1) * 16 + (f & 15);   // t<128
    int kbA = (f >> 4) * 8;
    int nB = n0 + (t >> 6) * 16 + (f & 15);
    int kbB = (f >> 4) * 8;
    float swv = sw[(mA / 196) * 4 + s];

    float ar[8], br[8];
    auto loadA = [&](int k0) {
        if (t < 128) {
            const float* base = pf + (size_t)(koff + k0 + kbA) * 1568 + mA;
            #pragma unroll
            for (int j = 0; j < 8; j++) ar[j] = base[(size_t)j * 1568] * swv;
        }
    };
    auto loadB = [&](int k0) {
        const float* base = W + (size_t)(koff + k0 + kbB) * 256 + nB;
        #pragma unroll
        for (int j = 0; j < 8; j++) br[j] = base[(size_t)j * 256];
    };

    loadA(0); loadB(0);
    for (int k0 = 0; k0 < klen; k0 += 32) {
        if (t < 128) *(bshort8*)&As[(((t >> 6) & 1) * 512 + f * 8)] = pack8(ar);
        *(bshort8*)&Bs[((t >> 6) * 512 + f * 8)] = pack8(br);
        __syncthreads();
        if (k0 + 32 < klen) { loadA(k0 + 32); loadB(k0 + 32); }
        bshort8 av = *(const bshort8*)&As[wm * 512 + lane * 8];
        bshort8 bv0 = *(const bshort8*)&Bs[(wn * 2 + 0) * 512 + lane * 8];
        bshort8 bv1 = *(const bshort8*)&Bs[(wn * 2 + 1) * 512 + lane * 8];
        acc0 = mfma16(av, bv0, acc0);
        acc1 = mfma16(av, bv1, acc1);
        __syncthreads();
    }
    int col0 = n0 + wn * 32 + (lane & 15);
    int rbase = m0 + wm * 16 + ((lane >> 4) << 2);
    #pragma unroll
    for (int r = 0; r < 4; r++) {
        int m = rbase + r;
        atomicAdd(&xtok[(size_t)m * 256 + col0], acc0[r]);
        atomicAdd(&xtok[(size_t)m * 256 + col0 + 16], acc1[r]);
    }
}

// -------- generic bf16-MFMA GEMM, fragment-direct staging + reg prefetch --------
template <bool B_IS_KXN>
__global__ __launch_bounds__(256) void gemm_kernel(
    const float* __restrict__ Ab, int lda, long long sAy, long long sAz,
    const float* __restrict__ Bb, int ldb, long long sBy, long long sBz,
    float* __restrict__ Cb, int ldc, long long sCy, long long sCz,
    const float* __restrict__ bias, int M, int N, int K,
    float alpha, int mtiles)
{
    const float* A = Ab + blockIdx.y * sAy + blockIdx.z * sAz;
    const float* B = Bb + blockIdx.y * sBy + blockIdx.z * sBz;
    float* C = Cb + blockIdx.y * sCy + blockIdx.z * sCz;
    int mt = blockIdx.x % mtiles, nt = blockIdx.x / mtiles;
    int m0 = mt * 32, n0 = nt * 64;
    __shared__ alignas(16) unsigned short As[1024];
    __shared__ alignas(16) unsigned short Bs[2048];
    int t = threadIdx.x, lane = t & 63, wid = t >> 6;
    int wm = wid >> 1, wn = wid & 1;
    f32x4 acc0 = {0, 0, 0, 0}, acc1 = {0, 0, 0, 0};

    int f = t & 63;
    int mA = m0 + ((t >> 6) & 1) * 16 + (f & 15);   // t<128
    int kbA = (f >> 4) * 8;
    int nB = n0 + (t >> 6) * 16 + (f & 15);
    int kbB = (f >> 4) * 8;

    float ar[8], br[8];
    auto loadA = [&](int k0) {
        if (t < 128) {
            int kb = k0 + kbA;
            if (mA < M && kb + 8 <= K) {
                const float4* p = (const float4*)(A + (size_t)mA * lda + kb);
                float4 u = p[0], v = p[1];
                ar[0] = u.x; ar[1] = u.y; ar[2] = u.z; ar[3] = u.w;
                ar[4] = v.x; ar[5] = v.y; ar[6] = v.z; ar[7] = v.w;
            } else {
                #pragma unroll
                for (int j = 0; j < 8; j++) {
                    int k = kb + j;
                    ar[j] = (mA < M && k < K) ? A[(size_t)mA * lda + k] : 0.f;
                }
            }
        }
    };
    auto loadB = [&](int k0) {
        int kb = k0 + kbB;
        if constexpr (B_IS_KXN) {
            #pragma unroll
            for (int j = 0; j < 8; j++) {
                int k = kb + j;
                br[j] = (k < K && nB < N) ? B[(size_t)k * ldb + nB] : 0.f;
            }
        } else {
            if (nB < N && kb + 8 <= K) {
                const float4* p = (const float4*)(B + (size_t)nB * ldb + kb);
                float4 u = p[0], v = p[1];
                br[0] = u.x; br[1] = u.y; br[2] = u.z; br[3] = u.w;
                br[4] = v.x; br[5] = v.y; br[6] = v.z; br[7] = v.w;
            } else {
                #pragma unroll
                for (int j = 0; j < 8; j++) {
                    int k = kb + j;
                    br[j] = (nB < N && k < K) ? B[(size_t)nB * ldb + k] : 0.f;
                }
            }
        }
    };

    loadA(0); loadB(0);
    for (int k0 = 0; k0 < K; k0 += 32) {
        if (t < 128) *(bshort8*)&As[(((t >> 6) & 1) * 512 + f * 8)] = pack8(ar);
        *(bshort8*)&Bs[((t >> 6) * 512 + f * 8)] = pack8(br);
        __syncthreads();
        if (k0 + 32 < K) { loadA(k0 + 32); loadB(k0 + 32); }
        bshort8 av = *(const bshort8*)&As[wm * 512 + lane * 8];
        bshort8 bv0 = *(const bshort8*)&Bs[(wn * 2 + 0) * 512 + lane * 8];
        bshort8 bv1 = *(const bshort8*)&Bs[(wn * 2 + 1) * 512 + lane * 8];
        acc0 = mfma16(av, bv0, acc0);
        acc1 = mfma16(av, bv1, acc1);
        __syncthreads();
    }
    int col0 = n0 + wn * 32 + (lane & 15);
    int rbase = m0 + wm * 16 + ((lane >> 4) << 2);
    #pragma unroll
    for (int r = 0; r < 4; r++) {
        int m = rbase + r;
        if (m < M) {
            if (col0 < N) {
                float v = acc0[r] * alpha;
                if (bias) v += bias[col0];
                C[(size_t)m * ldc + col0] = v;
            }
            int c1 = col0 + 16;
            if (c1 < N) {
                float v = acc1[r] * alpha;
                if (bias) v += bias[c1];
                C[(size_t)m * ldc + c1] = v;
            }
        }
    }
}

// -------- attention softmax over rows of S [12544][196], in place --------
__global__ __launch_bounds__(256) void attn_softmax(float* __restrict__ S)
{
    int wid = threadIdx.x >> 6, lane = threadIdx.x & 63;
    size_t row = (size_t)blockIdx.x * 4 + wid;
    float* p = S + row * 196;
    float v0 = p[lane];
    float v1 = p[64 + lane];
    float v2 = p[128 + lane];
    float v3 = (lane < 4) ? p[192 + lane] : -1e30f;
    float mx = fmaxf(fmaxf(v0, v1), fmaxf(v2, v3));
    #pragma unroll
    for (int off = 32; off > 0; off >>= 1) mx = fmaxf(mx, __shfl_xor(mx, off, 64));
    float e0 = expf(v0 - mx), e1 = expf(v1 - mx), e2 = expf(v2 - mx);
    float e3 = (lane < 4) ? expf(v3 - mx) : 0.f;
    float sum = e0 + e1 + e2 + e3;
    #pragma unroll
    for (int off = 32; off > 0; off >>= 1) sum += __shfl_xor(sum, off, 64);
    float inv = 1.f / sum;
    p[lane] = e0 * inv;
    p[64 + lane] = e1 * inv;
    p[128 + lane] = e2 * inv;
    if (lane < 4) p[192 + lane] = e3 * inv;
}

// -------- post-attn: gctx = mean(xo)@proj_w + proj_b ; lf = label_emb + gctx --------
__global__ __launch_bounds__(256) void projpost2(
    const float* __restrict__ xo, const float* __restrict__ proj_w,
    const float* __restrict__ proj_b, const float* __restrict__ lemb,
    float* __restrict__ lf)
{
    int b = blockIdx.x, t = threadIdx.x;
    __shared__ float xm[256];
    float s = 0.f;
    for (int n = 0; n < 196; n++) s += xo[((size_t)b * 196 + n) * 256 + t];
    xm[t] = s * (1.f / 196.f);
    __syncthreads();
    float g = proj_b[t];
    for (int k = 0; k < 256; k++) g += xm[k] * proj_w[k * 256 + t];
    for (int l = 0; l < 80; l++)
        lf[((size_t)b * 80 + l) * 256 + t] = lemb[l * 256 + t] + g;
}

// -------- Wa[h][which] = gat_W[h] @ a_{which} : [8][256] --------
__global__ __launch_bounds__(256) void wa_kernel(
    const float* __restrict__ gat_W, const float* __restrict__ gat_a,
    float* __restrict__ Wa)
{
    int h = blockIdx.x >> 1, which = blockIdx.x & 1, t = threadIdx.x;
    __shared__ float av[256];
    av[t] = gat_a[h * 512 + which * 256 + t];
    __syncthreads();
    float s = 0.f;
    const float* Wr = gat_W + (size_t)h * 65536 + (size_t)t * 256;
    for (int c = 0; c < 256; c++) s += Wr[c] * av[c];
    Wa[(h * 2 + which) * 256 + t] = s;
}

// -------- GAT attention scores -> atts (output 6), s-vectors from lf.Wa --------
__global__ __launch_bounds__(256) void gat_scores2(
    const float* __restrict__ lf, const float* __restrict__ Wa,
    float* __restrict__ atts)
{
    int b = blockIdx.x, h = blockIdx.y, t = threadIdx.x;
    __shared__ float s1[80], s2[80];
    if (t < 160) {
        int which = t / 80, l = t % 80;
        const float* row = lf + ((size_t)b * 80 + l) * 256;
        const float* av = Wa + (h * 2 + which) * 256;
        float acc = 0.f;
        for (int c = 0; c < 256; c++) acc += row[c] * av[c];
        if (which) s2[l] = acc; else s1[l] = acc;
    }
    __syncthreads();
    if (t < 80) {
        float si = s1[t];
        float mx = -1e30f;
        for (int j = 0; j < 80; j++) {
            float v = si + s2[j];
            v = v > 0.f ? v : 0.2f * v;
            mx = fmaxf(mx, v);
        }
        float sum = 0.f;
        for (int j = 0; j < 80; j++) {
            float v = si + s2[j];
            v = v > 0.f ? v : 0.2f * v;
            sum += expf(v - mx);
        }
        float inv = 1.f / sum;
        float* orow = atts + (size_t)h * 51200 + b * 6400 + t * 80;
        for (int j = 0; j < 80; j++) {
            float v = si + s2[j];
            v = v > 0.f ? v : 0.2f * v;
            orow[j] = expf(v - mx) * inv;
        }
    }
}

// -------- tail: attmean -> am_lf -> hmean -> agg -> final heads (outputs 0..4) --------
__global__ __launch_bounds__(256) void tail_kernel(
    const float* __restrict__ atts, const float* __restrict__ lf,
    const float* __restrict__ gat_W,
    const float* __restrict__ out_w, const float* __restrict__ out_b,
    const float* __restrict__ spec_w1, const float* __restrict__ spec_b1,
    const float* __restrict__ spec_w2, const float* __restrict__ spec_b2,
    const float* __restrict__ spat_w1, const float* __restrict__ spat_b1,
    const float* __restrict__ spat_w2, const float* __restrict__ spat_b2,
    const float* __restrict__ gate_w, const float* __restrict__ gate_b,
    const float* __restrict__ unc_w, const float* __restrict__ unc_b,
    float* __restrict__ out)
{
    int b = blockIdx.x, t = threadIdx.x;
    __shared__ float am[320];     // attmean[h][j]
    __shared__ float amlf[1024];  // (attmean @ lf)[h][c]
    __shared__ float hm[1024];    // cmean[h*256+c]
    __shared__ float a_s[256], h1[128], h2[128], alph[80];
    for (int s = t; s < 320; s += 256) {
        int h = s / 80, j = s - h * 80;
        const float* base = atts + (size_t)h * 51200 + b * 6400 + j;
        float acc = 0.f;
        for (int l = 0; l < 80; l++) acc += base[l * 80];
        am[s] = acc * (1.f / 80.f);
    }
    __syncthreads();
    #pragma unroll
    for (int h = 0; h < 4; h++) {
        float acc = 0.f;
        for (int l = 0; l < 80; l++) acc += am[h * 80 + l] * lf[((size_t)b * 80 + l) * 256 + t];
        amlf[h * 256 + t] = acc;
    }
    __syncthreads();
    #pragma unroll
    for (int h = 0; h < 4; h++) {
        float acc = 0.f;
        const float* Wp = gat_W + (size_t)h * 65536 + t;
        for (int k = 0; k < 256; k++) acc += amlf[h * 256 + k] * Wp[(size_t)k * 256];
        hm[h * 256 + t] = acc;
    }
    __syncthreads();
    {
        float acc = out_b[t];
        for (int k = 0; k < 1024; k++) acc += hm[k] * out_w[(size_t)k * 256 + t];
        a_s[t] = acc;
    }
    __syncthreads();
    if (t < 128) {
        float acc1 = spec_b1[t], acc2 = spat_b1[t];
        for (int c = 0; c < 256; c++) {
            acc1 += a_s[c] * spec_w1[c * 128 + t];
            acc2 += a_s[c] * spat_w1[c * 128 + t];
        }
        h1[t] = fmaxf(acc1, 0.f);
        h2[t] = fmaxf(acc2, 0.f);
    }
    __syncthreads();
    if (t < 80) {
        float sp = spec_b2[t], st = spat_b2[t];
        for (int c = 0; c < 128; c++) {
            sp += h1[c] * spec_w2[c * 80 + t];
            st += h2[c] * spat_w2[c * 80 + t];
        }
        float gz = gate_b[t], uz = unc_b[t];
        for (int c = 0; c < 256; c++) {
            gz += a_s[c] * gate_w[c * 80 + t];
            uz += a_s[c] * unc_w[c * 80 + t];
        }
        float g = 1.f / (1.f + expf(-gz));
        alph[t] = log1pf(expf(uz)) + 1.f;
        out[b * 80 + t] = g * sp + (1.f - g) * st;
        out[640 + b * 80 + t] = sp;
        out[1280 + b * 80 + t] = st;
        out[1920 + b * 80 + t] = g;
    }
    __syncthreads();
    if (t == 0) {
        float s = 0.f;
        for (int l = 0; l < 80; l++) s += alph[l];
        out[2560 + b] = 80.f / s;
    }
}

// ---------------- launcher ----------------
extern "C" void kernel_launch(void* const* d_in, const int* in_sizes, int n_in,
                              void* d_out, int out_size, void* d_ws, size_t ws_size,
                              hipStream_t stream)
{
    (void)in_sizes; (void)n_in; (void)out_size; (void)ws_size;
    const float* c2 = (const float*)d_in[0];
    const float* c3 = (const float*)d_in[1];
    const float* c4 = (const float*)d_in[2];
    const float* c5 = (const float*)d_in[3];
    const float* lat_w0 = (const float*)d_in[4];
    const float* lat_b0 = (const float*)d_in[5];
    const float* lat_w1 = (const float*)d_in[6];
    const float* lat_b1 = (const float*)d_in[7];
    const float* lat_w2 = (const float*)d_in[8];
    const float* lat_b2 = (const float*)d_in[9];
    const float* lat_w3 = (const float*)d_in[10];
    const float* lat_b3 = (const float*)d_in[11];
    const float* sp_w1 = (const float*)d_in[12];
    const float* sp_b1 = (const float*)d_in[13];
    const float* sp_w2 = (const float*)d_in[14];
    const float* sp_b2 = (const float*)d_in[15];
    const float* qkv_w = (const float*)d_in[16];
    const float* qkv_b = (const float*)d_in[17];
    const float* proj_w = (const float*)d_in[18];
    const float* proj_b = (const float*)d_in[19];
    const float* gat_W = (const float*)d_in[20];
    const float* gat_a = (const float*)d_in[21];
    const float* out_w = (const float*)d_in[22];
    const float* out_b = (const float*)d_in[23];
    const float* label_emb = (const float*)d_in[24];
    const float* spec_w1 = (const float*)d_in[25];
    const float* spec_b1 = (const float*)d_in[26];
    const float* spec_w2 = (const float*)d_in[27];
    const float* spec_b2 = (const float*)d_in[28];
    const float* spat_w1 = (const float*)d_in[29];
    const float* spat_b1 = (const float*)d_in[30];
    const float* spat_w2 = (const float*)d_in[31];
    const float* spat_b2 = (const float*)d_in[32];
    const float* gate_w = (const float*)d_in[33];
    const float* gate_b = (const float*)d_in[34];
    const float* unc_w = (const float*)d_in[35];
    const float* unc_b = (const float*)d_in[36];

    float* out = (float*)d_out;
    float* ws = (float*)d_ws;

    // workspace layout (floats); later phases reuse dead regions
    float* pf0    = ws + 0;        // 401408
    float* pf1    = ws + 401408;   // 802816
    float* pf2    = ws + 1204224;  // 1605632
    float* pf3    = ws + 2809856;  // 3211264 (ends 6021120)
    float* pooled = ws + 6021120;  // 16384
    float* beff   = ws + 6037504;  // 2048
    float* swpart = ws + 6039552;  // 32768
    float* qkv    = ws + 0;        // 1204224 (reuses pf0/pf1, dead after lateral)
    float* S      = ws + 1204224;  // 2458624 (reuses pf2/pf3)
    float* xo     = ws + 3662848;  // 401408
    float* lf     = ws + 4064256;  // 163840
    float* Wa     = ws + 4228096;  // 2048
    float* xtok   = ws + 6106112;  // 401408 (total 6507520 floats = 26.0 MB)

    float* swp  = out + 2568;  // sw [8,4] (output 5)
    float* atts = out + 2600;  // atts [4,8,80,80] (output 6)

    // 1. pool features of all scales to 14x14 (+ c5 global mean)
    pool_elem<112, 256, 8><<<1568, 256, 0, stream>>>(c2, pf0);
    pool_elem<56, 512, 6><<<3136, 256, 0, stream>>>(c3, pf1);
    pool_elem<28, 1024, 4><<<6272, 256, 0, stream>>>(c4, pf2);
    pool_elem<14, 2048, 3><<<12544, 256, 0, stream>>>(c5, pf3);
    c5_mean<<<4096, 256, 0, stream>>>(c5, pooled);
    // 2. scale weights + effective bias (split-K)
    sw_part<<<dim3(8, 8), 512, 0, stream>>>(pooled, sp_w1, swpart);
    sw_fin<<<8, 512, 0, stream>>>(swpart, sp_b1, sp_w2, sp_b2,
                                  lat_b0, lat_b1, lat_b2, lat_b3, swp, beff);
    // 3. lateral projection + sw combine -> x tokens [1568,256]
    xtok_init<<<1568, 256, 0, stream>>>(beff, xtok);
    lateral_slice<<<dim3(196, 8), 256, 0, stream>>>(pf0, pf1, pf2, pf3,
                                                    lat_w0, lat_w1, lat_w2, lat_w3,
                                                    swp, xtok);
    // 4. qkv = x @ qkv_w + qkv_b : [1568,768]
    gemm_kernel<true><<<dim3(49 * 12, 1, 1), 256, 0, stream>>>(
        xtok, 256, 0, 0, qkv_w, 768, 0, 0, qkv, 768, 0, 0,
        qkv_b, 1568, 768, 256, 1.f, 49);
    // 5. S = q @ k^T * hd^-0.5, per (b,h) : [64,196,196]
    gemm_kernel<false><<<dim3(7 * 4, 8, 8), 256, 0, stream>>>(
        qkv, 768, 150528, 32, qkv + 256, 768, 150528, 32,
        S, 196, 307328, 38416, nullptr, 196, 196, 32, 0.17677669529663687f, 7);
    // 6. row softmax on S (in place)
    attn_softmax<<<3136, 256, 0, stream>>>(S);
    // 7. xo = P @ v : [1568,256] (head-concat layout)
    gemm_kernel<true><<<dim3(7, 8, 8), 256, 0, stream>>>(
        S, 196, 307328, 38416, qkv + 512, 768, 150528, 32,
        xo, 256, 50176, 32, nullptr, 196, 32, 196, 1.f, 7);
    // 8. gctx (mean-commuted proj) + lf
    projpost2<<<8, 256, 0, stream>>>(xo, proj_w, proj_b, label_emb, lf);
    // 9. Wa = gat_W @ a-halves
    wa_kernel<<<8, 256, 0, stream>>>(gat_W, gat_a, Wa);
    // 10. GAT attention -> atts (output 6)
    gat_scores2<<<dim3(8, 4), 256, 0, stream>>>(lf, Wa, atts);
    // 11. tail: attmean -> agg -> final heads (outputs 0..4)
    tail_kernel<<<8, 256, 0, stream>>>(atts, lf, gat_W, out_w, out_b,
        spec_w1, spec_b1, spec_w2, spec_b2,
        spat_w1, spat_b1, spat_w2, spat_b2,
        gate_w, gate_b, unc_w, unc_b, out);
}

// Round 5
// 540.225 us; speedup vs baseline: 2.0991x; 1.1073x over previous
//
#include <hip/hip_runtime.h>
#include <math.h>

typedef __attribute__((ext_vector_type(8))) short bshort8;
typedef __attribute__((ext_vector_type(4))) float f32x4;

#define DI __device__ __forceinline__

DI unsigned short f2bf(float x) {
    unsigned int u = __builtin_bit_cast(unsigned int, x);
    u += 0x7fffu + ((u >> 16) & 1u);
    return (unsigned short)(u >> 16);
}

DI bshort8 pack8(const float* v) {
    bshort8 r;
    #pragma unroll
    for (int j = 0; j < 8; j++) r[j] = (short)f2bf(v[j]);
    return r;
}

DI f32x4 mfma16(bshort8 a, bshort8 b, f32x4 c) {
    return __builtin_amdgcn_mfma_f32_16x16x32_bf16(a, b, c, 0, 0, 0);
}

// ---- composite (bilinear resize N->112, align_corners=False) + 8x8 avgpool stencils ----
__device__ const float W14[14][3] = {
    {0.875f, 0.125f, 0.f},
    {0.125f, 0.75f, 0.125f}, {0.125f, 0.75f, 0.125f}, {0.125f, 0.75f, 0.125f},
    {0.125f, 0.75f, 0.125f}, {0.125f, 0.75f, 0.125f}, {0.125f, 0.75f, 0.125f},
    {0.125f, 0.75f, 0.125f}, {0.125f, 0.75f, 0.125f}, {0.125f, 0.75f, 0.125f},
    {0.125f, 0.75f, 0.125f}, {0.125f, 0.75f, 0.125f}, {0.125f, 0.75f, 0.125f},
    {0.125f, 0.875f, 0.f}};
__device__ const float W28[14][4] = {
    {0.5f, 0.4375f, 0.0625f, 0.f},
    {0.0625f, 0.4375f, 0.4375f, 0.0625f}, {0.0625f, 0.4375f, 0.4375f, 0.0625f},
    {0.0625f, 0.4375f, 0.4375f, 0.0625f}, {0.0625f, 0.4375f, 0.4375f, 0.0625f},
    {0.0625f, 0.4375f, 0.4375f, 0.0625f}, {0.0625f, 0.4375f, 0.4375f, 0.0625f},
    {0.0625f, 0.4375f, 0.4375f, 0.0625f}, {0.0625f, 0.4375f, 0.4375f, 0.0625f},
    {0.0625f, 0.4375f, 0.4375f, 0.0625f}, {0.0625f, 0.4375f, 0.4375f, 0.0625f},
    {0.0625f, 0.4375f, 0.4375f, 0.0625f}, {0.0625f, 0.4375f, 0.4375f, 0.0625f},
    {0.0625f, 0.4375f, 0.5f, 0.f}};
__device__ const float W56[14][6] = {
    {0.25f, 0.25f, 0.25f, 0.21875f, 0.03125f, 0.f},
    {0.03125f, 0.21875f, 0.25f, 0.25f, 0.21875f, 0.03125f},
    {0.03125f, 0.21875f, 0.25f, 0.25f, 0.21875f, 0.03125f},
    {0.03125f, 0.21875f, 0.25f, 0.25f, 0.21875f, 0.03125f},
    {0.03125f, 0.21875f, 0.25f, 0.25f, 0.21875f, 0.03125f},
    {0.03125f, 0.21875f, 0.25f, 0.25f, 0.21875f, 0.03125f},
    {0.03125f, 0.21875f, 0.25f, 0.25f, 0.21875f, 0.03125f},
    {0.03125f, 0.21875f, 0.25f, 0.25f, 0.21875f, 0.03125f},
    {0.03125f, 0.21875f, 0.25f, 0.25f, 0.21875f, 0.03125f},
    {0.03125f, 0.21875f, 0.25f, 0.25f, 0.21875f, 0.03125f},
    {0.03125f, 0.21875f, 0.25f, 0.25f, 0.21875f, 0.03125f},
    {0.03125f, 0.21875f, 0.25f, 0.25f, 0.21875f, 0.03125f},
    {0.03125f, 0.21875f, 0.25f, 0.25f, 0.21875f, 0.03125f},
    {0.03125f, 0.21875f, 0.25f, 0.25f, 0.25f, 0.f}};

// -------- K1: one thread per pooled output; pf layout [cin][1568], col = b*196 + r --------
template <int N, int C, int TAPS>
__global__ __launch_bounds__(256) void pool_elem(
    const float* __restrict__ src, float* __restrict__ dst)
{
    unsigned id = blockIdx.x * 256u + threadIdx.x;
    unsigned p = id / 196u;
    unsigned r = id - p * 196u;
    unsigned ti = r / 14u, tj = r - ti * 14u;
    unsigned b = p / C, cin = p - b * C;
    const float* plane = src + (size_t)p * (N * N);
    float acc = 0.f;
    if constexpr (N == 112) {
        const float4* p4 = (const float4*)(plane + (size_t)(ti * 8) * 112 + tj * 8);
        #pragma unroll
        for (int i = 0; i < 8; i++) {
            float4 u = p4[i * 28];
            float4 v = p4[i * 28 + 1];
            acc += (u.x + u.y) + (u.z + u.w) + (v.x + v.y) + (v.z + v.w);
        }
        acc *= (1.f / 64.f);
    } else {
        constexpr int STRIDE = N / 14;
        const float (*WT)[TAPS] = (N == 14) ? (const float (*)[TAPS])W14
                                : (N == 28) ? (const float (*)[TAPS])W28
                                            : (const float (*)[TAPS])W56;
        int hs = (int)(STRIDE * ti) - 1; if (hs < 0) hs = 0;
        int ws = (int)(STRIDE * tj) - 1; if (ws < 0) ws = 0;
        float wh[TAPS], ww[TAPS];
        #pragma unroll
        for (int i = 0; i < TAPS; i++) { wh[i] = WT[ti][i]; ww[i] = WT[tj][i]; }
        #pragma unroll
        for (int i = 0; i < TAPS; i++) {
            int hi = hs + i; if (hi > N - 1) hi = N - 1;
            const float* row = plane + (size_t)hi * N;
            float rs = 0.f;
            #pragma unroll
            for (int j = 0; j < TAPS; j++) {
                int wj = ws + j; if (wj > N - 1) wj = N - 1;
                rs += ww[j] * row[wj];
            }
            acc += wh[i] * rs;
        }
    }
    dst[(size_t)cin * 1568 + b * 196 + r] = acc;
}

// -------- K1b: c5 global mean, one wave per plane --------
__global__ __launch_bounds__(256) void c5_mean(
    const float* __restrict__ c5, float* __restrict__ pooled)
{
    int wid = threadIdx.x >> 6, lane = threadIdx.x & 63;
    int p = blockIdx.x * 4 + wid;
    const float* plane = c5 + (size_t)p * 196;
    float v = plane[lane] + plane[64 + lane] + plane[128 + lane];
    if (lane < 4) v += plane[192 + lane];
    #pragma unroll
    for (int off = 32; off > 0; off >>= 1) v += __shfl_xor(v, off, 64);
    if (lane == 0) pooled[p] = v * (1.f / 196.f);
}

// -------- K2a: partial GEMV for scale-weight MLP layer 1 (split-K) --------
__global__ __launch_bounds__(512) void sw_part(
    const float* __restrict__ pooled, const float* __restrict__ sp_w1,
    float* __restrict__ partial)
{
    int b = blockIdx.x, kc = blockIdx.y, t = threadIdx.x;
    __shared__ float ps[256];
    if (t < 256) ps[t] = pooled[b * 2048 + kc * 256 + t];
    __syncthreads();
    float acc = 0.f;
    const float* w = sp_w1 + (size_t)(kc * 256) * 512 + t;
    #pragma unroll 4
    for (int c = 0; c < 256; c++) acc += ps[c] * w[(size_t)c * 512];
    partial[((size_t)b * 8 + kc) * 512 + t] = acc;
}

// -------- K2b: finish sw MLP --------
__global__ __launch_bounds__(512) void sw_fin(
    const float* __restrict__ partial, const float* __restrict__ sp_b1,
    const float* __restrict__ sp_w2, const float* __restrict__ sp_b2,
    const float* __restrict__ lb0, const float* __restrict__ lb1,
    const float* __restrict__ lb2, const float* __restrict__ lb3,
    float* __restrict__ sw_out, float* __restrict__ beff)
{
    int b = blockIdx.x, t = threadIdx.x;
    __shared__ float h[512];
    __shared__ float s4s[4];
    __shared__ float swl[4];
    float a = sp_b1[t];
    #pragma unroll
    for (int kc = 0; kc < 8; kc++) a += partial[((size_t)b * 8 + kc) * 512 + t];
    h[t] = fmaxf(a, 0.f);
    __syncthreads();
    int wv = t >> 6, lane = t & 63;
    if (wv < 4) {
        float acc = 0.f;
        #pragma unroll
        for (int i = 0; i < 8; i++) {
            int idx = lane + 64 * i;
            acc += h[idx] * sp_w2[idx * 4 + wv];
        }
        #pragma unroll
        for (int off = 32; off > 0; off >>= 1) acc += __shfl_xor(acc, off, 64);
        if (lane == 0) s4s[wv] = acc + sp_b2[wv];
    }
    __syncthreads();
    if (t == 0) {
        float mx = fmaxf(fmaxf(s4s[0], s4s[1]), fmaxf(s4s[2], s4s[3]));
        float e0 = expf(s4s[0] - mx), e1 = expf(s4s[1] - mx);
        float e2 = expf(s4s[2] - mx), e3 = expf(s4s[3] - mx);
        float inv = 1.f / (e0 + e1 + e2 + e3);
        swl[0] = e0 * inv; swl[1] = e1 * inv; swl[2] = e2 * inv; swl[3] = e3 * inv;
        for (int o = 0; o < 4; o++) sw_out[b * 4 + o] = swl[o];
    }
    __syncthreads();
    if (t < 256)
        beff[b * 256 + t] = swl[0] * lb0[t] + swl[1] * lb1[t] + swl[2] * lb2[t] + swl[3] * lb3[t];
}

// -------- K3a: init xtok with effective bias --------
__global__ __launch_bounds__(256) void xtok_init(
    const float* __restrict__ beff, float* __restrict__ xtok)
{
    int m = blockIdx.x, c = threadIdx.x;
    xtok[(size_t)m * 256 + c] = beff[(m / 196) * 256 + c];
}

// -------- K3b: lateral projection, fragment-direct staging, split into 8 K-slices --------
__global__ __launch_bounds__(256) void lateral_slice(
    const float* __restrict__ pf0, const float* __restrict__ pf1,
    const float* __restrict__ pf2, const float* __restrict__ pf3,
    const float* __restrict__ w0, const float* __restrict__ w1,
    const float* __restrict__ w2, const float* __restrict__ w3,
    const float* __restrict__ sw, float* __restrict__ xtok)
{
    const int sArr[8]    = {0, 1, 2, 2, 3, 3, 3, 3};
    const int koffArr[8] = {0, 0, 0, 512, 0, 512, 1024, 1536};
    const int klenArr[8] = {256, 512, 512, 512, 512, 512, 512, 512};
    int sl = blockIdx.y;
    int s = sArr[sl], koff = koffArr[sl], klen = klenArr[sl];
    const float* pf = (s == 0) ? pf0 : (s == 1) ? pf1 : (s == 2) ? pf2 : pf3;
    const float* W  = (s == 0) ? w0  : (s == 1) ? w1  : (s == 2) ? w2  : w3;

    int mt = blockIdx.x % 49, nt = blockIdx.x / 49;
    int m0 = mt * 32, n0 = nt * 64;
    __shared__ alignas(16) unsigned short As[1024];
    __shared__ alignas(16) unsigned short Bs[2048];
    int t = threadIdx.x, lane = t & 63, wid = t >> 6;
    int wm = wid >> 1, wn = wid & 1;
    f32x4 acc0 = {0, 0, 0, 0}, acc1 = {0, 0, 0, 0};

    int f = t & 63;
    int mA = m0 + ((t >> 6) & 1) * 16 + (f & 15);   // t<128
    int kbA = (f >> 4) * 8;
    int nB = n0 + (t >> 6) * 16 + (f & 15);
    int kbB = (f >> 4) * 8;
    float swv = sw[(mA / 196) * 4 + s];

    float ar[8], br[8];
    auto loadA = [&](int k0) {
        if (t < 128) {
            const float* base = pf + (size_t)(koff + k0 + kbA) * 1568 + mA;
            #pragma unroll
            for (int j = 0; j < 8; j++) ar[j] = base[(size_t)j * 1568] * swv;
        }
    };
    auto loadB = [&](int k0) {
        const float* base = W + (size_t)(koff + k0 + kbB) * 256 + nB;
        #pragma unroll
        for (int j = 0; j < 8; j++) br[j] = base[(size_t)j * 256];
    };

    loadA(0); loadB(0);
    for (int k0 = 0; k0 < klen; k0 += 32) {
        if (t < 128) *(bshort8*)&As[(((t >> 6) & 1) * 512 + f * 8)] = pack8(ar);
        *(bshort8*)&Bs[((t >> 6) * 512 + f * 8)] = pack8(br);
        __syncthreads();
        if (k0 + 32 < klen) { loadA(k0 + 32); loadB(k0 + 32); }
        bshort8 av = *(const bshort8*)&As[wm * 512 + lane * 8];
        bshort8 bv0 = *(const bshort8*)&Bs[(wn * 2 + 0) * 512 + lane * 8];
        bshort8 bv1 = *(const bshort8*)&Bs[(wn * 2 + 1) * 512 + lane * 8];
        acc0 = mfma16(av, bv0, acc0);
        acc1 = mfma16(av, bv1, acc1);
        __syncthreads();
    }
    int col0 = n0 + wn * 32 + (lane & 15);
    int rbase = m0 + wm * 16 + ((lane >> 4) << 2);
    #pragma unroll
    for (int r = 0; r < 4; r++) {
        int m = rbase + r;
        atomicAdd(&xtok[(size_t)m * 256 + col0], acc0[r]);
        atomicAdd(&xtok[(size_t)m * 256 + col0 + 16], acc1[r]);
    }
}

// -------- generic bf16-MFMA GEMM, fragment-direct staging + reg prefetch --------
template <bool B_IS_KXN>
__global__ __launch_bounds__(256) void gemm_kernel(
    const float* __restrict__ Ab, int lda, long long sAy, long long sAz,
    const float* __restrict__ Bb, int ldb, long long sBy, long long sBz,
    float* __restrict__ Cb, int ldc, long long sCy, long long sCz,
    const float* __restrict__ bias, int M, int N, int K,
    float alpha, int mtiles)
{
    const float* A = Ab + blockIdx.y * sAy + blockIdx.z * sAz;
    const float* B = Bb + blockIdx.y * sBy + blockIdx.z * sBz;
    float* C = Cb + blockIdx.y * sCy + blockIdx.z * sCz;
    int mt = blockIdx.x % mtiles, nt = blockIdx.x / mtiles;
    int m0 = mt * 32, n0 = nt * 64;
    __shared__ alignas(16) unsigned short As[1024];
    __shared__ alignas(16) unsigned short Bs[2048];
    int t = threadIdx.x, lane = t & 63, wid = t >> 6;
    int wm = wid >> 1, wn = wid & 1;
    f32x4 acc0 = {0, 0, 0, 0}, acc1 = {0, 0, 0, 0};

    int f = t & 63;
    int mA = m0 + ((t >> 6) & 1) * 16 + (f & 15);   // t<128
    int kbA = (f >> 4) * 8;
    int nB = n0 + (t >> 6) * 16 + (f & 15);
    int kbB = (f >> 4) * 8;

    float ar[8], br[8];
    auto loadA = [&](int k0) {
        if (t < 128) {
            int kb = k0 + kbA;
            if (mA < M && kb + 8 <= K) {
                const float4* p = (const float4*)(A + (size_t)mA * lda + kb);
                float4 u = p[0], v = p[1];
                ar[0] = u.x; ar[1] = u.y; ar[2] = u.z; ar[3] = u.w;
                ar[4] = v.x; ar[5] = v.y; ar[6] = v.z; ar[7] = v.w;
            } else {
                #pragma unroll
                for (int j = 0; j < 8; j++) {
                    int k = kb + j;
                    ar[j] = (mA < M && k < K) ? A[(size_t)mA * lda + k] : 0.f;
                }
            }
        }
    };
    auto loadB = [&](int k0) {
        int kb = k0 + kbB;
        if constexpr (B_IS_KXN) {
            #pragma unroll
            for (int j = 0; j < 8; j++) {
                int k = kb + j;
                br[j] = (k < K && nB < N) ? B[(size_t)k * ldb + nB] : 0.f;
            }
        } else {
            if (nB < N && kb + 8 <= K) {
                const float4* p = (const float4*)(B + (size_t)nB * ldb + kb);
                float4 u = p[0], v = p[1];
                br[0] = u.x; br[1] = u.y; br[2] = u.z; br[3] = u.w;
                br[4] = v.x; br[5] = v.y; br[6] = v.z; br[7] = v.w;
            } else {
                #pragma unroll
                for (int j = 0; j < 8; j++) {
                    int k = kb + j;
                    br[j] = (nB < N && k < K) ? B[(size_t)nB * ldb + k] : 0.f;
                }
            }
        }
    };

    loadA(0); loadB(0);
    for (int k0 = 0; k0 < K; k0 += 32) {
        if (t < 128) *(bshort8*)&As[(((t >> 6) & 1) * 512 + f * 8)] = pack8(ar);
        *(bshort8*)&Bs[((t >> 6) * 512 + f * 8)] = pack8(br);
        __syncthreads();
        if (k0 + 32 < K) { loadA(k0 + 32); loadB(k0 + 32); }
        bshort8 av = *(const bshort8*)&As[wm * 512 + lane * 8];
        bshort8 bv0 = *(const bshort8*)&Bs[(wn * 2 + 0) * 512 + lane * 8];
        bshort8 bv1 = *(const bshort8*)&Bs[(wn * 2 + 1) * 512 + lane * 8];
        acc0 = mfma16(av, bv0, acc0);
        acc1 = mfma16(av, bv1, acc1);
        __syncthreads();
    }
    int col0 = n0 + wn * 32 + (lane & 15);
    int rbase = m0 + wm * 16 + ((lane >> 4) << 2);
    #pragma unroll
    for (int r = 0; r < 4; r++) {
        int m = rbase + r;
        if (m < M) {
            if (col0 < N) {
                float v = acc0[r] * alpha;
                if (bias) v += bias[col0];
                C[(size_t)m * ldc + col0] = v;
            }
            int c1 = col0 + 16;
            if (c1 < N) {
                float v = acc1[r] * alpha;
                if (bias) v += bias[c1];
                C[(size_t)m * ldc + c1] = v;
            }
        }
    }
}

// -------- attention softmax over rows of S [12544][196], in place --------
__global__ __launch_bounds__(256) void attn_softmax(float* __restrict__ S)
{
    int wid = threadIdx.x >> 6, lane = threadIdx.x & 63;
    size_t row = (size_t)blockIdx.x * 4 + wid;
    float* p = S + row * 196;
    float v0 = p[lane];
    float v1 = p[64 + lane];
    float v2 = p[128 + lane];
    float v3 = (lane < 4) ? p[192 + lane] : -1e30f;
    float mx = fmaxf(fmaxf(v0, v1), fmaxf(v2, v3));
    #pragma unroll
    for (int off = 32; off > 0; off >>= 1) mx = fmaxf(mx, __shfl_xor(mx, off, 64));
    float e0 = expf(v0 - mx), e1 = expf(v1 - mx), e2 = expf(v2 - mx);
    float e3 = (lane < 4) ? expf(v3 - mx) : 0.f;
    float sum = e0 + e1 + e2 + e3;
    #pragma unroll
    for (int off = 32; off > 0; off >>= 1) sum += __shfl_xor(sum, off, 64);
    float inv = 1.f / sum;
    p[lane] = e0 * inv;
    p[64 + lane] = e1 * inv;
    p[128 + lane] = e2 * inv;
    if (lane < 4) p[192 + lane] = e3 * inv;
}

// -------- xo token-mean partials: xopart[b][g][t] = sum of 28 tokens --------
__global__ __launch_bounds__(256) void xo_part(
    const float* __restrict__ xo, float* __restrict__ xopart)
{
    int b = blockIdx.x, g = blockIdx.y, t = threadIdx.x;
    const float* base = xo + ((size_t)b * 196 + g * 28) * 256 + t;
    float s = 0.f;
    #pragma unroll
    for (int n = 0; n < 28; n++) s += base[(size_t)n * 256];
    xopart[(b * 7 + g) * 256 + t] = s;
}

// -------- gctx partials: gpart[b][kc][t] over 64-k slice of proj_w --------
__global__ __launch_bounds__(256) void gctx_part(
    const float* __restrict__ xopart, const float* __restrict__ proj_w,
    float* __restrict__ gpart)
{
    int b = blockIdx.x, kc = blockIdx.y, t = threadIdx.x;
    __shared__ float xm[64];
    if (t < 64) {
        float s = 0.f;
        #pragma unroll
        for (int g = 0; g < 7; g++) s += xopart[(b * 7 + g) * 256 + kc * 64 + t];
        xm[t] = s * (1.f / 196.f);
    }
    __syncthreads();
    float acc = 0.f;
    const float* w = proj_w + (size_t)(kc * 64) * 256 + t;
    #pragma unroll 8
    for (int j = 0; j < 64; j++) acc += xm[j] * w[(size_t)j * 256];
    gpart[(b * 4 + kc) * 256 + t] = acc;
}

// -------- lf write: lf[b,l,t] = lemb + proj_b + sum of gctx partials --------
__global__ __launch_bounds__(256) void lf_write(
    const float* __restrict__ gpart, const float* __restrict__ proj_b,
    const float* __restrict__ lemb, float* __restrict__ lf)
{
    int b = blockIdx.x, l = blockIdx.y, t = threadIdx.x;
    float g = proj_b[t] + gpart[(b * 4 + 0) * 256 + t] + gpart[(b * 4 + 1) * 256 + t]
            + gpart[(b * 4 + 2) * 256 + t] + gpart[(b * 4 + 3) * 256 + t];
    lf[((size_t)b * 80 + l) * 256 + t] = lemb[l * 256 + t] + g;
}

// -------- Wa[h][which][c] = dot(gat_W[h][c][:], a_which); both halves, one gat_W pass --------
__global__ __launch_bounds__(256) void wa2(
    const float* __restrict__ gat_W, const float* __restrict__ gat_a,
    float* __restrict__ Wa)
{
    int h = blockIdx.x, q = blockIdx.y;
    int t = threadIdx.x, w = t >> 6, lane = t & 63;
    __shared__ float a1[256], a2[256];
    a1[t] = gat_a[h * 512 + t];
    a2[t] = gat_a[h * 512 + 256 + t];
    __syncthreads();
    for (int ci = 0; ci < 16; ci++) {
        int c = q * 64 + w * 16 + ci;
        const float* row = gat_W + (size_t)h * 65536 + (size_t)c * 256;
        float p1 = 0.f, p2 = 0.f;
        #pragma unroll
        for (int jj = 0; jj < 4; jj++) {
            float v = row[lane + 64 * jj];
            p1 += v * a1[lane + 64 * jj];
            p2 += v * a2[lane + 64 * jj];
        }
        #pragma unroll
        for (int off = 32; off > 0; off >>= 1) {
            p1 += __shfl_xor(p1, off, 64);
            p2 += __shfl_xor(p2, off, 64);
        }
        if (lane == 0) { Wa[h * 512 + c] = p1; Wa[h * 512 + 256 + c] = p2; }
    }
}

// -------- s12[b][pair][l] = dot(lf[b,l,:], Wa[pair]); pair = h*2+which --------
__global__ __launch_bounds__(256) void s12_kernel(
    const float* __restrict__ lf, const float* __restrict__ Wa,
    float* __restrict__ s12)
{
    int l = blockIdx.x, b = blockIdx.y, t = threadIdx.x, w = t >> 6, lane = t & 63;
    __shared__ float row[256];
    row[t] = lf[((size_t)b * 80 + l) * 256 + t];
    __syncthreads();
    #pragma unroll
    for (int pp = 0; pp < 2; pp++) {
        int pair = w * 2 + pp;
        float p = 0.f;
        #pragma unroll
        for (int jj = 0; jj < 4; jj++) {
            int c = lane + 64 * jj;
            p += row[c] * Wa[pair * 256 + c];
        }
        #pragma unroll
        for (int off = 32; off > 0; off >>= 1) p += __shfl_xor(p, off, 64);
        if (lane == 0) s12[(b * 8 + pair) * 80 + l] = p;
    }
}

// -------- GAT softmax rows: one wave per (b,h,i) row -> atts (output 6) --------
__global__ __launch_bounds__(256) void gat_rows(
    const float* __restrict__ s12, float* __restrict__ atts)
{
    int b = blockIdx.x, h = blockIdx.y, z = blockIdx.z;
    int t = threadIdx.x, w = t >> 6, lane = t & 63;
    int i = z * 4 + w;
    float s1i = s12[(b * 8 + h * 2) * 80 + i];
    const float* s2 = s12 + (b * 8 + h * 2 + 1) * 80;
    float v0 = s1i + s2[lane]; v0 = v0 > 0.f ? v0 : 0.2f * v0;
    float v1 = -1e30f;
    if (lane < 16) { v1 = s1i + s2[64 + lane]; v1 = v1 > 0.f ? v1 : 0.2f * v1; }
    float mx = fmaxf(v0, v1);
    #pragma unroll
    for (int off = 32; off > 0; off >>= 1) mx = fmaxf(mx, __shfl_xor(mx, off, 64));
    float e0 = expf(v0 - mx), e1 = (lane < 16) ? expf(v1 - mx) : 0.f;
    float sum = e0 + e1;
    #pragma unroll
    for (int off = 32; off > 0; off >>= 1) sum += __shfl_xor(sum, off, 64);
    float inv = 1.f / sum;
    float* orow = atts + (size_t)h * 51200 + b * 6400 + i * 80;
    orow[lane] = e0 * inv;
    if (lane < 16) orow[64 + lane] = e1 * inv;
}

// -------- am (col-mean of atts) + amlf[b][h][t] = sum_l am[l]*lf[b,l,t] --------
__global__ __launch_bounds__(256) void amlf_kernel(
    const float* __restrict__ atts, const float* __restrict__ lf,
    float* __restrict__ amlf)
{
    int b = blockIdx.x, h = blockIdx.y, t = threadIdx.x;
    __shared__ float am[80];
    if (t < 80) {
        const float* base = atts + (size_t)h * 51200 + b * 6400 + t;
        float acc = 0.f;
        for (int l = 0; l < 80; l++) acc += base[l * 80];
        am[t] = acc * (1.f / 80.f);
    }
    __syncthreads();
    float acc = 0.f;
    const float* lfb = lf + (size_t)b * 80 * 256 + t;
    #pragma unroll 4
    for (int l = 0; l < 80; l++) acc += am[l] * lfb[(size_t)l * 256];
    amlf[(b * 4 + h) * 256 + t] = acc;
}

// -------- hm partials: hmpart[b][h][kc][t] over 64-k slice of gat_W[h] --------
__global__ __launch_bounds__(256) void hm_part(
    const float* __restrict__ amlf, const float* __restrict__ gat_W,
    float* __restrict__ hmpart)
{
    int b = blockIdx.x, h = blockIdx.y, kc = blockIdx.z, t = threadIdx.x;
    __shared__ float av[64];
    if (t < 64) av[t] = amlf[(b * 4 + h) * 256 + kc * 64 + t];
    __syncthreads();
    float acc = 0.f;
    const float* w = gat_W + (size_t)h * 65536 + (size_t)(kc * 64) * 256 + t;
    #pragma unroll 8
    for (int j = 0; j < 64; j++) acc += av[j] * w[(size_t)j * 256];
    hmpart[((b * 4 + h) * 4 + kc) * 256 + t] = acc;
}

// -------- a_s partials: aspart[b][kc][t] over 64-k slice of out_w --------
__global__ __launch_bounds__(256) void as_part(
    const float* __restrict__ hmpart, const float* __restrict__ out_w,
    float* __restrict__ aspart)
{
    int b = blockIdx.x, kc = blockIdx.y, t = threadIdx.x;
    __shared__ float hv[64];
    if (t < 64) {
        int hk = kc * 64 + t;           // 0..1023, head-concat index
        int h = hk >> 8, c = hk & 255;
        const float* p = hmpart + ((size_t)(b * 4 + h) * 4) * 256 + c;
        hv[t] = p[0] + p[256] + p[512] + p[768];
    }
    __syncthreads();
    float acc = 0.f;
    const float* w = out_w + (size_t)(kc * 64) * 256 + t;
    #pragma unroll 8
    for (int j = 0; j < 64; j++) acc += hv[j] * w[(size_t)j * 256];
    aspart[(b * 16 + kc) * 256 + t] = acc;
}

// -------- final heads (outputs 0..4); work split across all 256 threads --------
__global__ __launch_bounds__(256) void final2(
    const float* __restrict__ aspart, const float* __restrict__ out_b,
    const float* __restrict__ spec_w1, const float* __restrict__ spec_b1,
    const float* __restrict__ spec_w2, const float* __restrict__ spec_b2,
    const float* __restrict__ spat_w1, const float* __restrict__ spat_b1,
    const float* __restrict__ spat_w2, const float* __restrict__ spat_b2,
    const float* __restrict__ gate_w, const float* __restrict__ gate_b,
    const float* __restrict__ unc_w, const float* __restrict__ unc_b,
    float* __restrict__ out)
{
    int b = blockIdx.x, t = threadIdx.x;
    __shared__ float a_s[256], h1[128], h2[128];
    __shared__ float spv[80], stv[80], gzv[80], alph[80];
    float acc = out_b[t];
    #pragma unroll
    for (int kc = 0; kc < 16; kc++) acc += aspart[(b * 16 + kc) * 256 + t];
    a_s[t] = acc;
    __syncthreads();
    {   // layer1 of both MLP branches: t<128 -> spec, t>=128 -> spat
        int o = t & 127;
        const float* w1 = (t < 128) ? spec_w1 : spat_w1;
        float a1 = (t < 128) ? spec_b1[o] : spat_b1[o];
        #pragma unroll 4
        for (int c = 0; c < 256; c++) a1 += a_s[c] * w1[c * 128 + o];
        if (t < 128) h1[o] = fmaxf(a1, 0.f); else h2[o] = fmaxf(a1, 0.f);
    }
    __syncthreads();
    if (t < 80) {
        float sp = spec_b2[t];
        for (int c = 0; c < 128; c++) sp += h1[c] * spec_w2[c * 80 + t];
        float gz = gate_b[t];
        #pragma unroll 4
        for (int c = 0; c < 256; c++) gz += a_s[c] * gate_w[c * 80 + t];
        spv[t] = sp; gzv[t] = gz;
    } else if (t >= 128 && t < 208) {
        int o = t - 128;
        float st = spat_b2[o];
        for (int c = 0; c < 128; c++) st += h2[c] * spat_w2[c * 80 + o];
        float uz = unc_b[o];
        #pragma unroll 4
        for (int c = 0; c < 256; c++) uz += a_s[c] * unc_w[c * 80 + o];
        stv[o] = st; alph[o] = log1pf(expf(uz)) + 1.f;
    }
    __syncthreads();
    if (t < 80) {
        float g = 1.f / (1.f + expf(-gzv[t]));
        out[b * 80 + t] = g * spv[t] + (1.f - g) * stv[t];
        out[640 + b * 80 + t] = spv[t];
        out[1280 + b * 80 + t] = stv[t];
        out[1920 + b * 80 + t] = g;
    }
    __syncthreads();
    if (t == 0) {
        float s = 0.f;
        for (int l = 0; l < 80; l++) s += alph[l];
        out[2560 + b] = 80.f / s;
    }
}

// ---------------- launcher ----------------
extern "C" void kernel_launch(void* const* d_in, const int* in_sizes, int n_in,
                              void* d_out, int out_size, void* d_ws, size_t ws_size,
                              hipStream_t stream)
{
    (void)in_sizes; (void)n_in; (void)out_size; (void)ws_size;
    const float* c2 = (const float*)d_in[0];
    const float* c3 = (const float*)d_in[1];
    const float* c4 = (const float*)d_in[2];
    const float* c5 = (const float*)d_in[3];
    const float* lat_w0 = (const float*)d_in[4];
    const float* lat_b0 = (const float*)d_in[5];
    const float* lat_w1 = (const float*)d_in[6];
    const float* lat_b1 = (const float*)d_in[7];
    const float* lat_w2 = (const float*)d_in[8];
    const float* lat_b2 = (const float*)d_in[9];
    const float* lat_w3 = (const float*)d_in[10];
    const float* lat_b3 = (const float*)d_in[11];
    const float* sp_w1 = (const float*)d_in[12];
    const float* sp_b1 = (const float*)d_in[13];
    const float* sp_w2 = (const float*)d_in[14];
    const float* sp_b2 = (const float*)d_in[15];
    const float* qkv_w = (const float*)d_in[16];
    const float* qkv_b = (const float*)d_in[17];
    const float* proj_w = (const float*)d_in[18];
    const float* proj_b = (const float*)d_in[19];
    const float* gat_W = (const float*)d_in[20];
    const float* gat_a = (const float*)d_in[21];
    const float* out_w = (const float*)d_in[22];
    const float* out_b = (const float*)d_in[23];
    const float* label_emb = (const float*)d_in[24];
    const float* spec_w1 = (const float*)d_in[25];
    const float* spec_b1 = (const float*)d_in[26];
    const float* spec_w2 = (const float*)d_in[27];
    const float* spec_b2 = (const float*)d_in[28];
    const float* spat_w1 = (const float*)d_in[29];
    const float* spat_b1 = (const float*)d_in[30];
    const float* spat_w2 = (const float*)d_in[31];
    const float* spat_b2 = (const float*)d_in[32];
    const float* gate_w = (const float*)d_in[33];
    const float* gate_b = (const float*)d_in[34];
    const float* unc_w = (const float*)d_in[35];
    const float* unc_b = (const float*)d_in[36];

    float* out = (float*)d_out;
    float* ws = (float*)d_ws;

    // workspace layout (floats); later phases reuse dead regions
    float* pf0    = ws + 0;        // 401408
    float* pf1    = ws + 401408;
    float* pf2    = ws + 1204224;
    float* pf3    = ws + 2809856;  // ends 6021120
    float* pooled = ws + 6021120;  // 16384
    float* beff   = ws + 6037504;  // 2048
    float* swpart = ws + 6039552;  // 32768
    float* qkv    = ws + 0;        // reuses pf0/pf1 (dead after lateral)
    float* S      = ws + 1204224;  // reuses pf2/pf3
    float* xo     = ws + 3662848;  // 401408
    float* lf     = ws + 4064256;  // 163840 (ends 4228096)
    float* Wa     = ws + 4228096;  // 2048
    float* xopart = ws + 4230144;  // 14336
    float* gpart  = ws + 4244480;  // 8192
    float* s12    = ws + 4252672;  // 5120
    float* amlf   = ws + 4257792;  // 8192
    float* hmpart = ws + 4265984;  // 32768
    float* aspart = ws + 4298752;  // 32768 (ends 4331520)
    float* xtok   = ws + 6106112;  // 401408

    float* swp  = out + 2568;  // sw [8,4] (output 5)
    float* atts = out + 2600;  // atts [4,8,80,80] (output 6)

    // 1. pool features of all scales to 14x14 (+ c5 global mean)
    pool_elem<112, 256, 8><<<1568, 256, 0, stream>>>(c2, pf0);
    pool_elem<56, 512, 6><<<3136, 256, 0, stream>>>(c3, pf1);
    pool_elem<28, 1024, 4><<<6272, 256, 0, stream>>>(c4, pf2);
    pool_elem<14, 2048, 3><<<12544, 256, 0, stream>>>(c5, pf3);
    c5_mean<<<4096, 256, 0, stream>>>(c5, pooled);
    // 2. scale weights + effective bias (split-K)
    sw_part<<<dim3(8, 8), 512, 0, stream>>>(pooled, sp_w1, swpart);
    sw_fin<<<8, 512, 0, stream>>>(swpart, sp_b1, sp_w2, sp_b2,
                                  lat_b0, lat_b1, lat_b2, lat_b3, swp, beff);
    // 3. lateral projection + sw combine -> x tokens [1568,256]
    xtok_init<<<1568, 256, 0, stream>>>(beff, xtok);
    lateral_slice<<<dim3(196, 8), 256, 0, stream>>>(pf0, pf1, pf2, pf3,
                                                    lat_w0, lat_w1, lat_w2, lat_w3,
                                                    swp, xtok);
    // 4. qkv = x @ qkv_w + qkv_b : [1568,768]
    gemm_kernel<true><<<dim3(49 * 12, 1, 1), 256, 0, stream>>>(
        xtok, 256, 0, 0, qkv_w, 768, 0, 0, qkv, 768, 0, 0,
        qkv_b, 1568, 768, 256, 1.f, 49);
    // 5. S = q @ k^T * hd^-0.5, per (b,h) : [64,196,196]
    gemm_kernel<false><<<dim3(7 * 4, 8, 8), 256, 0, stream>>>(
        qkv, 768, 150528, 32, qkv + 256, 768, 150528, 32,
        S, 196, 307328, 38416, nullptr, 196, 196, 32, 0.17677669529663687f, 7);
    // 6. row softmax on S (in place)
    attn_softmax<<<3136, 256, 0, stream>>>(S);
    // 7. xo = P @ v : [1568,256] (head-concat layout)
    gemm_kernel<true><<<dim3(7, 8, 8), 256, 0, stream>>>(
        S, 196, 307328, 38416, qkv + 512, 768, 150528, 32,
        xo, 256, 50176, 32, nullptr, 196, 32, 196, 1.f, 7);
    // 8. gctx (mean-commuted proj) + lf, split-K parallel
    xo_part<<<dim3(8, 7), 256, 0, stream>>>(xo, xopart);
    gctx_part<<<dim3(8, 4), 256, 0, stream>>>(xopart, proj_w, gpart);
    lf_write<<<dim3(8, 80), 256, 0, stream>>>(gpart, proj_b, label_emb, lf);
    // 9. Wa = gat_W rows . a-halves (both halves, one pass)
    wa2<<<dim3(4, 4), 256, 0, stream>>>(gat_W, gat_a, Wa);
    // 10. GAT scores s1/s2, then row softmax -> atts (output 6)
    s12_kernel<<<dim3(80, 8), 256, 0, stream>>>(lf, Wa, s12);
    gat_rows<<<dim3(8, 4, 20), 256, 0, stream>>>(s12, atts);
    // 11. tail: attmean/amlf -> hm partials -> a_s partials -> final heads
    amlf_kernel<<<dim3(8, 4), 256, 0, stream>>>(atts, lf, amlf);
    hm_part<<<dim3(8, 4, 4), 256, 0, stream>>>(amlf, gat_W, hmpart);
    as_part<<<dim3(8, 16), 256, 0, stream>>>(hmpart, out_w, aspart);
    final2<<<8, 256, 0, stream>>>(aspart, out_b,
        spec_w1, spec_b1, spec_w2, spec_b2,
        spat_w1, spat_b1, spat_w2, spat_b2,
        gate_w, gate_b, unc_w, unc_b, out);
}

// Round 6
// 485.255 us; speedup vs baseline: 2.3369x; 1.1133x over previous
//
#include <hip/hip_runtime.h>
#include <math.h>

typedef __attribute__((ext_vector_type(8))) short bshort8;
typedef __attribute__((ext_vector_type(4))) float f32x4;

#define DI __device__ __forceinline__

DI unsigned short f2bf(float x) {
    unsigned int u = __builtin_bit_cast(unsigned int, x);
    u += 0x7fffu + ((u >> 16) & 1u);
    return (unsigned short)(u >> 16);
}

DI bshort8 pack8(const float* v) {
    bshort8 r;
    #pragma unroll
    for (int j = 0; j < 8; j++) r[j] = (short)f2bf(v[j]);
    return r;
}

DI f32x4 mfma16(bshort8 a, bshort8 b, f32x4 c) {
    return __builtin_amdgcn_mfma_f32_16x16x32_bf16(a, b, c, 0, 0, 0);
}

// ---- composite (bilinear resize N->112, align_corners=False) + 8x8 avgpool stencils ----
__device__ const float W14[14][3] = {
    {0.875f, 0.125f, 0.f},
    {0.125f, 0.75f, 0.125f}, {0.125f, 0.75f, 0.125f}, {0.125f, 0.75f, 0.125f},
    {0.125f, 0.75f, 0.125f}, {0.125f, 0.75f, 0.125f}, {0.125f, 0.75f, 0.125f},
    {0.125f, 0.75f, 0.125f}, {0.125f, 0.75f, 0.125f}, {0.125f, 0.75f, 0.125f},
    {0.125f, 0.75f, 0.125f}, {0.125f, 0.75f, 0.125f}, {0.125f, 0.75f, 0.125f},
    {0.125f, 0.875f, 0.f}};
__device__ const float W28[14][4] = {
    {0.5f, 0.4375f, 0.0625f, 0.f},
    {0.0625f, 0.4375f, 0.4375f, 0.0625f}, {0.0625f, 0.4375f, 0.4375f, 0.0625f},
    {0.0625f, 0.4375f, 0.4375f, 0.0625f}, {0.0625f, 0.4375f, 0.4375f, 0.0625f},
    {0.0625f, 0.4375f, 0.4375f, 0.0625f}, {0.0625f, 0.4375f, 0.4375f, 0.0625f},
    {0.0625f, 0.4375f, 0.4375f, 0.0625f}, {0.0625f, 0.4375f, 0.4375f, 0.0625f},
    {0.0625f, 0.4375f, 0.4375f, 0.0625f}, {0.0625f, 0.4375f, 0.4375f, 0.0625f},
    {0.0625f, 0.4375f, 0.4375f, 0.0625f}, {0.0625f, 0.4375f, 0.4375f, 0.0625f},
    {0.0625f, 0.4375f, 0.5f, 0.f}};
__device__ const float W56[14][6] = {
    {0.25f, 0.25f, 0.25f, 0.21875f, 0.03125f, 0.f},
    {0.03125f, 0.21875f, 0.25f, 0.25f, 0.21875f, 0.03125f},
    {0.03125f, 0.21875f, 0.25f, 0.25f, 0.21875f, 0.03125f},
    {0.03125f, 0.21875f, 0.25f, 0.25f, 0.21875f, 0.03125f},
    {0.03125f, 0.21875f, 0.25f, 0.25f, 0.21875f, 0.03125f},
    {0.03125f, 0.21875f, 0.25f, 0.25f, 0.21875f, 0.03125f},
    {0.03125f, 0.21875f, 0.25f, 0.25f, 0.21875f, 0.03125f},
    {0.03125f, 0.21875f, 0.25f, 0.25f, 0.21875f, 0.03125f},
    {0.03125f, 0.21875f, 0.25f, 0.25f, 0.21875f, 0.03125f},
    {0.03125f, 0.21875f, 0.25f, 0.25f, 0.21875f, 0.03125f},
    {0.03125f, 0.21875f, 0.25f, 0.25f, 0.21875f, 0.03125f},
    {0.03125f, 0.21875f, 0.25f, 0.25f, 0.21875f, 0.03125f},
    {0.03125f, 0.21875f, 0.25f, 0.25f, 0.21875f, 0.03125f},
    {0.03125f, 0.21875f, 0.25f, 0.25f, 0.25f, 0.f}};

// -------- K1: one thread per pooled output; pf layout [cin][1568], col = b*196 + r --------
template <int N, int C, int TAPS>
__global__ __launch_bounds__(256) void pool_elem(
    const float* __restrict__ src, float* __restrict__ dst)
{
    unsigned id = blockIdx.x * 256u + threadIdx.x;
    unsigned p = id / 196u;
    unsigned r = id - p * 196u;
    unsigned ti = r / 14u, tj = r - ti * 14u;
    unsigned b = p / C, cin = p - b * C;
    const float* plane = src + (size_t)p * (N * N);
    float acc = 0.f;
    if constexpr (N == 112) {
        const float4* p4 = (const float4*)(plane + (size_t)(ti * 8) * 112 + tj * 8);
        #pragma unroll
        for (int i = 0; i < 8; i++) {
            float4 u = p4[i * 28];
            float4 v = p4[i * 28 + 1];
            acc += (u.x + u.y) + (u.z + u.w) + (v.x + v.y) + (v.z + v.w);
        }
        acc *= (1.f / 64.f);
    } else {
        constexpr int STRIDE = N / 14;
        const float (*WT)[TAPS] = (N == 14) ? (const float (*)[TAPS])W14
                                : (N == 28) ? (const float (*)[TAPS])W28
                                            : (const float (*)[TAPS])W56;
        int hs = (int)(STRIDE * ti) - 1; if (hs < 0) hs = 0;
        int ws = (int)(STRIDE * tj) - 1; if (ws < 0) ws = 0;
        float wh[TAPS], ww[TAPS];
        #pragma unroll
        for (int i = 0; i < TAPS; i++) { wh[i] = WT[ti][i]; ww[i] = WT[tj][i]; }
        #pragma unroll
        for (int i = 0; i < TAPS; i++) {
            int hi = hs + i; if (hi > N - 1) hi = N - 1;
            const float* row = plane + (size_t)hi * N;
            float rs = 0.f;
            #pragma unroll
            for (int j = 0; j < TAPS; j++) {
                int wj = ws + j; if (wj > N - 1) wj = N - 1;
                rs += ww[j] * row[wj];
            }
            acc += wh[i] * rs;
        }
    }
    dst[(size_t)cin * 1568 + b * 196 + r] = acc;
}

// -------- K1b: c5 global mean, one wave per plane --------
__global__ __launch_bounds__(256) void c5_mean(
    const float* __restrict__ c5, float* __restrict__ pooled)
{
    int wid = threadIdx.x >> 6, lane = threadIdx.x & 63;
    int p = blockIdx.x * 4 + wid;
    const float* plane = c5 + (size_t)p * 196;
    float v = plane[lane] + plane[64 + lane] + plane[128 + lane];
    if (lane < 4) v += plane[192 + lane];
    #pragma unroll
    for (int off = 32; off > 0; off >>= 1) v += __shfl_xor(v, off, 64);
    if (lane == 0) pooled[p] = v * (1.f / 196.f);
}

// -------- K2a: partial GEMV for scale-weight MLP layer 1 (split-K) --------
__global__ __launch_bounds__(512) void sw_part(
    const float* __restrict__ pooled, const float* __restrict__ sp_w1,
    float* __restrict__ partial)
{
    int b = blockIdx.x, kc = blockIdx.y, t = threadIdx.x;
    __shared__ float ps[256];
    if (t < 256) ps[t] = pooled[b * 2048 + kc * 256 + t];
    __syncthreads();
    float acc = 0.f;
    const float* w = sp_w1 + (size_t)(kc * 256) * 512 + t;
    #pragma unroll 8
    for (int c = 0; c < 256; c++) acc += ps[c] * w[(size_t)c * 512];
    partial[((size_t)b * 8 + kc) * 512 + t] = acc;
}

// -------- K2b: finish sw MLP --------
__global__ __launch_bounds__(512) void sw_fin(
    const float* __restrict__ partial, const float* __restrict__ sp_b1,
    const float* __restrict__ sp_w2, const float* __restrict__ sp_b2,
    const float* __restrict__ lb0, const float* __restrict__ lb1,
    const float* __restrict__ lb2, const float* __restrict__ lb3,
    float* __restrict__ sw_out, float* __restrict__ beff)
{
    int b = blockIdx.x, t = threadIdx.x;
    __shared__ float h[512];
    __shared__ float s4s[4];
    __shared__ float swl[4];
    float a = sp_b1[t];
    #pragma unroll
    for (int kc = 0; kc < 8; kc++) a += partial[((size_t)b * 8 + kc) * 512 + t];
    h[t] = fmaxf(a, 0.f);
    __syncthreads();
    int wv = t >> 6, lane = t & 63;
    if (wv < 4) {
        float acc = 0.f;
        #pragma unroll
        for (int i = 0; i < 8; i++) {
            int idx = lane + 64 * i;
            acc += h[idx] * sp_w2[idx * 4 + wv];
        }
        #pragma unroll
        for (int off = 32; off > 0; off >>= 1) acc += __shfl_xor(acc, off, 64);
        if (lane == 0) s4s[wv] = acc + sp_b2[wv];
    }
    __syncthreads();
    if (t == 0) {
        float mx = fmaxf(fmaxf(s4s[0], s4s[1]), fmaxf(s4s[2], s4s[3]));
        float e0 = expf(s4s[0] - mx), e1 = expf(s4s[1] - mx);
        float e2 = expf(s4s[2] - mx), e3 = expf(s4s[3] - mx);
        float inv = 1.f / (e0 + e1 + e2 + e3);
        swl[0] = e0 * inv; swl[1] = e1 * inv; swl[2] = e2 * inv; swl[3] = e3 * inv;
        for (int o = 0; o < 4; o++) sw_out[b * 4 + o] = swl[o];
    }
    __syncthreads();
    if (t < 256)
        beff[b * 256 + t] = swl[0] * lb0[t] + swl[1] * lb1[t] + swl[2] * lb2[t] + swl[3] * lb3[t];
}

// -------- K3a: init xtok with effective bias --------
__global__ __launch_bounds__(256) void xtok_init(
    const float* __restrict__ beff, float* __restrict__ xtok)
{
    int m = blockIdx.x, c = threadIdx.x;
    xtok[(size_t)m * 256 + c] = beff[(m / 196) * 256 + c];
}

// -------- K3b: lateral projection, fragment-direct staging, split into 8 K-slices --------
__global__ __launch_bounds__(256) void lateral_slice(
    const float* __restrict__ pf0, const float* __restrict__ pf1,
    const float* __restrict__ pf2, const float* __restrict__ pf3,
    const float* __restrict__ w0, const float* __restrict__ w1,
    const float* __restrict__ w2, const float* __restrict__ w3,
    const float* __restrict__ sw, float* __restrict__ xtok)
{
    const int sArr[8]    = {0, 1, 2, 2, 3, 3, 3, 3};
    const int koffArr[8] = {0, 0, 0, 512, 0, 512, 1024, 1536};
    const int klenArr[8] = {256, 512, 512, 512, 512, 512, 512, 512};
    int sl = blockIdx.y;
    int s = sArr[sl], koff = koffArr[sl], klen = klenArr[sl];
    const float* pf = (s == 0) ? pf0 : (s == 1) ? pf1 : (s == 2) ? pf2 : pf3;
    const float* W  = (s == 0) ? w0  : (s == 1) ? w1  : (s == 2) ? w2  : w3;

    int mt = blockIdx.x % 49, nt = blockIdx.x / 49;
    int m0 = mt * 32, n0 = nt * 64;
    __shared__ alignas(16) unsigned short As[1024];
    __shared__ alignas(16) unsigned short Bs[2048];
    int t = threadIdx.x, lane = t & 63, wid = t >> 6;
    int wm = wid >> 1, wn = wid & 1;
    f32x4 acc0 = {0, 0, 0, 0}, acc1 = {0, 0, 0, 0};

    int f = t & 63;
    int mA = m0 + ((t >> 6) & 1) * 16 + (f & 15);   // t<128
    int kbA = (f >> 4) * 8;
    int nB = n0 + (t >> 6) * 16 + (f & 15);
    int kbB = (f >> 4) * 8;
    float swv = sw[(mA / 196) * 4 + s];

    float ar[8], br[8];
    auto loadA = [&](int k0) {
        if (t < 128) {
            const float* base = pf + (size_t)(koff + k0 + kbA) * 1568 + mA;
            #pragma unroll
            for (int j = 0; j < 8; j++) ar[j] = base[(size_t)j * 1568] * swv;
        }
    };
    auto loadB = [&](int k0) {
        const float* base = W + (size_t)(koff + k0 + kbB) * 256 + nB;
        #pragma unroll
        for (int j = 0; j < 8; j++) br[j] = base[(size_t)j * 256];
    };

    loadA(0); loadB(0);
    for (int k0 = 0; k0 < klen; k0 += 32) {
        if (t < 128) *(bshort8*)&As[(((t >> 6) & 1) * 512 + f * 8)] = pack8(ar);
        *(bshort8*)&Bs[((t >> 6) * 512 + f * 8)] = pack8(br);
        __syncthreads();
        if (k0 + 32 < klen) { loadA(k0 + 32); loadB(k0 + 32); }
        bshort8 av = *(const bshort8*)&As[wm * 512 + lane * 8];
        bshort8 bv0 = *(const bshort8*)&Bs[(wn * 2 + 0) * 512 + lane * 8];
        bshort8 bv1 = *(const bshort8*)&Bs[(wn * 2 + 1) * 512 + lane * 8];
        acc0 = mfma16(av, bv0, acc0);
        acc1 = mfma16(av, bv1, acc1);
        __syncthreads();
    }
    int col0 = n0 + wn * 32 + (lane & 15);
    int rbase = m0 + wm * 16 + ((lane >> 4) << 2);
    #pragma unroll
    for (int r = 0; r < 4; r++) {
        int m = rbase + r;
        atomicAdd(&xtok[(size_t)m * 256 + col0], acc0[r]);
        atomicAdd(&xtok[(size_t)m * 256 + col0 + 16], acc1[r]);
    }
}

// -------- generic bf16-MFMA GEMM, fragment-direct staging + reg prefetch --------
template <bool B_IS_KXN>
__global__ __launch_bounds__(256) void gemm_kernel(
    const float* __restrict__ Ab, int lda, long long sAy, long long sAz,
    const float* __restrict__ Bb, int ldb, long long sBy, long long sBz,
    float* __restrict__ Cb, int ldc, long long sCy, long long sCz,
    const float* __restrict__ bias, int M, int N, int K,
    float alpha, int mtiles)
{
    const float* A = Ab + blockIdx.y * sAy + blockIdx.z * sAz;
    const float* B = Bb + blockIdx.y * sBy + blockIdx.z * sBz;
    float* C = Cb + blockIdx.y * sCy + blockIdx.z * sCz;
    int mt = blockIdx.x % mtiles, nt = blockIdx.x / mtiles;
    int m0 = mt * 32, n0 = nt * 64;
    __shared__ alignas(16) unsigned short As[1024];
    __shared__ alignas(16) unsigned short Bs[2048];
    int t = threadIdx.x, lane = t & 63, wid = t >> 6;
    int wm = wid >> 1, wn = wid & 1;
    f32x4 acc0 = {0, 0, 0, 0}, acc1 = {0, 0, 0, 0};

    int f = t & 63;
    int mA = m0 + ((t >> 6) & 1) * 16 + (f & 15);   // t<128
    int kbA = (f >> 4) * 8;
    int nB = n0 + (t >> 6) * 16 + (f & 15);
    int kbB = (f >> 4) * 8;

    float ar[8], br[8];
    auto loadA = [&](int k0) {
        if (t < 128) {
            int kb = k0 + kbA;
            if (mA < M && kb + 8 <= K) {
                const float4* p = (const float4*)(A + (size_t)mA * lda + kb);
                float4 u = p[0], v = p[1];
                ar[0] = u.x; ar[1] = u.y; ar[2] = u.z; ar[3] = u.w;
                ar[4] = v.x; ar[5] = v.y; ar[6] = v.z; ar[7] = v.w;
            } else {
                #pragma unroll
                for (int j = 0; j < 8; j++) {
                    int k = kb + j;
                    ar[j] = (mA < M && k < K) ? A[(size_t)mA * lda + k] : 0.f;
                }
            }
        }
    };
    auto loadB = [&](int k0) {
        int kb = k0 + kbB;
        if constexpr (B_IS_KXN) {
            #pragma unroll
            for (int j = 0; j < 8; j++) {
                int k = kb + j;
                br[j] = (k < K && nB < N) ? B[(size_t)k * ldb + nB] : 0.f;
            }
        } else {
            if (nB < N && kb + 8 <= K) {
                const float4* p = (const float4*)(B + (size_t)nB * ldb + kb);
                float4 u = p[0], v = p[1];
                br[0] = u.x; br[1] = u.y; br[2] = u.z; br[3] = u.w;
                br[4] = v.x; br[5] = v.y; br[6] = v.z; br[7] = v.w;
            } else {
                #pragma unroll
                for (int j = 0; j < 8; j++) {
                    int k = kb + j;
                    br[j] = (nB < N && k < K) ? B[(size_t)nB * ldb + k] : 0.f;
                }
            }
        }
    };

    loadA(0); loadB(0);
    for (int k0 = 0; k0 < K; k0 += 32) {
        if (t < 128) *(bshort8*)&As[(((t >> 6) & 1) * 512 + f * 8)] = pack8(ar);
        *(bshort8*)&Bs[((t >> 6) * 512 + f * 8)] = pack8(br);
        __syncthreads();
        if (k0 + 32 < K) { loadA(k0 + 32); loadB(k0 + 32); }
        bshort8 av = *(const bshort8*)&As[wm * 512 + lane * 8];
        bshort8 bv0 = *(const bshort8*)&Bs[(wn * 2 + 0) * 512 + lane * 8];
        bshort8 bv1 = *(const bshort8*)&Bs[(wn * 2 + 1) * 512 + lane * 8];
        acc0 = mfma16(av, bv0, acc0);
        acc1 = mfma16(av, bv1, acc1);
        __syncthreads();
    }
    int col0 = n0 + wn * 32 + (lane & 15);
    int rbase = m0 + wm * 16 + ((lane >> 4) << 2);
    #pragma unroll
    for (int r = 0; r < 4; r++) {
        int m = rbase + r;
        if (m < M) {
            if (col0 < N) {
                float v = acc0[r] * alpha;
                if (bias) v += bias[col0];
                C[(size_t)m * ldc + col0] = v;
            }
            int c1 = col0 + 16;
            if (c1 < N) {
                float v = acc1[r] * alpha;
                if (bias) v += bias[c1];
                C[(size_t)m * ldc + c1] = v;
            }
        }
    }
}

// -------- attention softmax over rows of S [12544][196], in place --------
__global__ __launch_bounds__(256) void attn_softmax(float* __restrict__ S)
{
    int wid = threadIdx.x >> 6, lane = threadIdx.x & 63;
    size_t row = (size_t)blockIdx.x * 4 + wid;
    float* p = S + row * 196;
    float v0 = p[lane];
    float v1 = p[64 + lane];
    float v2 = p[128 + lane];
    float v3 = (lane < 4) ? p[192 + lane] : -1e30f;
    float mx = fmaxf(fmaxf(v0, v1), fmaxf(v2, v3));
    #pragma unroll
    for (int off = 32; off > 0; off >>= 1) mx = fmaxf(mx, __shfl_xor(mx, off, 64));
    float e0 = expf(v0 - mx), e1 = expf(v1 - mx), e2 = expf(v2 - mx);
    float e3 = (lane < 4) ? expf(v3 - mx) : 0.f;
    float sum = e0 + e1 + e2 + e3;
    #pragma unroll
    for (int off = 32; off > 0; off >>= 1) sum += __shfl_xor(sum, off, 64);
    float inv = 1.f / sum;
    p[lane] = e0 * inv;
    p[64 + lane] = e1 * inv;
    p[128 + lane] = e2 * inv;
    if (lane < 4) p[192 + lane] = e3 * inv;
}

// -------- xo token-mean partials: xopart[b][g][t] = sum of 28 tokens --------
__global__ __launch_bounds__(256) void xo_part(
    const float* __restrict__ xo, float* __restrict__ xopart)
{
    int b = blockIdx.x, g = blockIdx.y, t = threadIdx.x;
    const float* base = xo + ((size_t)b * 196 + g * 28) * 256 + t;
    float s = 0.f;
    #pragma unroll
    for (int n = 0; n < 28; n++) s += base[(size_t)n * 256];
    xopart[(b * 7 + g) * 256 + t] = s;
}

// -------- gctx partials: gpart[b][kc][t] over 64-k slice of proj_w --------
__global__ __launch_bounds__(256) void gctx_part(
    const float* __restrict__ xopart, const float* __restrict__ proj_w,
    float* __restrict__ gpart)
{
    int b = blockIdx.x, kc = blockIdx.y, t = threadIdx.x;
    __shared__ float xm[64];
    if (t < 64) {
        float s = 0.f;
        #pragma unroll
        for (int g = 0; g < 7; g++) s += xopart[(b * 7 + g) * 256 + kc * 64 + t];
        xm[t] = s * (1.f / 196.f);
    }
    __syncthreads();
    float acc = 0.f;
    const float* w = proj_w + (size_t)(kc * 64) * 256 + t;
    #pragma unroll 8
    for (int j = 0; j < 64; j++) acc += xm[j] * w[(size_t)j * 256];
    gpart[(b * 4 + kc) * 256 + t] = acc;
}

// -------- Wa[h][which][c] = dot(gat_W[h][c][:], a_which); both halves, one gat_W pass --------
__global__ __launch_bounds__(256) void wa2(
    const float* __restrict__ gat_W, const float* __restrict__ gat_a,
    float* __restrict__ Wa)
{
    int h = blockIdx.x, q = blockIdx.y;
    int t = threadIdx.x, w = t >> 6, lane = t & 63;
    __shared__ float a1[256], a2[256];
    a1[t] = gat_a[h * 512 + t];
    a2[t] = gat_a[h * 512 + 256 + t];
    __syncthreads();
    for (int ci = 0; ci < 16; ci++) {
        int c = q * 64 + w * 16 + ci;
        const float* row = gat_W + (size_t)h * 65536 + (size_t)c * 256;
        float p1 = 0.f, p2 = 0.f;
        #pragma unroll
        for (int jj = 0; jj < 4; jj++) {
            float v = row[lane + 64 * jj];
            p1 += v * a1[lane + 64 * jj];
            p2 += v * a2[lane + 64 * jj];
        }
        #pragma unroll
        for (int off = 32; off > 0; off >>= 1) {
            p1 += __shfl_xor(p1, off, 64);
            p2 += __shfl_xor(p2, off, 64);
        }
        if (lane == 0) { Wa[h * 512 + c] = p1; Wa[h * 512 + 256 + c] = p2; }
    }
}

// -------- fused: lf[b,l,:] = lemb + gctx ; s12[b][pair][l] = dot(lf row, Wa[pair]) --------
__global__ __launch_bounds__(256) void lf_s12(
    const float* __restrict__ gpart, const float* __restrict__ proj_b,
    const float* __restrict__ lemb, const float* __restrict__ Wa,
    float* __restrict__ lf, float* __restrict__ s12)
{
    int l = blockIdx.x, b = blockIdx.y, t = threadIdx.x;
    int w = t >> 6, lane = t & 63;
    __shared__ float row[256];
    float g = proj_b[t] + gpart[(b * 4 + 0) * 256 + t] + gpart[(b * 4 + 1) * 256 + t]
            + gpart[(b * 4 + 2) * 256 + t] + gpart[(b * 4 + 3) * 256 + t];
    float v = lemb[l * 256 + t] + g;
    lf[((size_t)b * 80 + l) * 256 + t] = v;
    row[t] = v;
    __syncthreads();
    #pragma unroll
    for (int pp = 0; pp < 2; pp++) {
        int pair = w * 2 + pp;
        float p = 0.f;
        #pragma unroll
        for (int jj = 0; jj < 4; jj++) {
            int c = lane + 64 * jj;
            p += row[c] * Wa[pair * 256 + c];
        }
        #pragma unroll
        for (int off = 32; off > 0; off >>= 1) p += __shfl_xor(p, off, 64);
        if (lane == 0) s12[(b * 8 + pair) * 80 + l] = p;
    }
}

// -------- GAT softmax rows: one wave per (b,h,i) row -> atts (output 6) --------
__global__ __launch_bounds__(256) void gat_rows(
    const float* __restrict__ s12, float* __restrict__ atts)
{
    int b = blockIdx.x, h = blockIdx.y, z = blockIdx.z;
    int t = threadIdx.x, w = t >> 6, lane = t & 63;
    int i = z * 4 + w;
    float s1i = s12[(b * 8 + h * 2) * 80 + i];
    const float* s2 = s12 + (b * 8 + h * 2 + 1) * 80;
    float v0 = s1i + s2[lane]; v0 = v0 > 0.f ? v0 : 0.2f * v0;
    float v1 = -1e30f;
    if (lane < 16) { v1 = s1i + s2[64 + lane]; v1 = v1 > 0.f ? v1 : 0.2f * v1; }
    float mx = fmaxf(v0, v1);
    #pragma unroll
    for (int off = 32; off > 0; off >>= 1) mx = fmaxf(mx, __shfl_xor(mx, off, 64));
    float e0 = expf(v0 - mx), e1 = (lane < 16) ? expf(v1 - mx) : 0.f;
    float sum = e0 + e1;
    #pragma unroll
    for (int off = 32; off > 0; off >>= 1) sum += __shfl_xor(sum, off, 64);
    float inv = 1.f / sum;
    float* orow = atts + (size_t)h * 51200 + b * 6400 + i * 80;
    orow[lane] = e0 * inv;
    if (lane < 16) orow[64 + lane] = e1 * inv;
}

// -------- am (col-mean of atts) + amlf[b][h][t] = sum_l am[l]*lf[b,l,t] --------
__global__ __launch_bounds__(256) void amlf_kernel(
    const float* __restrict__ atts, const float* __restrict__ lf,
    float* __restrict__ amlf)
{
    int b = blockIdx.x, h = blockIdx.y, t = threadIdx.x;
    __shared__ float am[80];
    if (t < 80) {
        const float* base = atts + (size_t)h * 51200 + b * 6400 + t;
        float acc = 0.f;
        #pragma unroll 8
        for (int l = 0; l < 80; l++) acc += base[l * 80];
        am[t] = acc * (1.f / 80.f);
    }
    __syncthreads();
    float acc = 0.f;
    const float* lfb = lf + (size_t)b * 80 * 256 + t;
    #pragma unroll 8
    for (int l = 0; l < 80; l++) acc += am[l] * lfb[(size_t)l * 256];
    amlf[(b * 4 + h) * 256 + t] = acc;
}

// -------- hm partials: hmpart[b][h][kc][t] over 64-k slice of gat_W[h] --------
__global__ __launch_bounds__(256) void hm_part(
    const float* __restrict__ amlf, const float* __restrict__ gat_W,
    float* __restrict__ hmpart)
{
    int b = blockIdx.x, h = blockIdx.y, kc = blockIdx.z, t = threadIdx.x;
    __shared__ float av[64];
    if (t < 64) av[t] = amlf[(b * 4 + h) * 256 + kc * 64 + t];
    __syncthreads();
    float acc = 0.f;
    const float* w = gat_W + (size_t)h * 65536 + (size_t)(kc * 64) * 256 + t;
    #pragma unroll 8
    for (int j = 0; j < 64; j++) acc += av[j] * w[(size_t)j * 256];
    hmpart[((b * 4 + h) * 4 + kc) * 256 + t] = acc;
}

// -------- a_s partials: aspart[b][kc][t] over 64-k slice of out_w --------
__global__ __launch_bounds__(256) void as_part(
    const float* __restrict__ hmpart, const float* __restrict__ out_w,
    float* __restrict__ aspart)
{
    int b = blockIdx.x, kc = blockIdx.y, t = threadIdx.x;
    __shared__ float hv[64];
    if (t < 64) {
        int hk = kc * 64 + t;
        int h = hk >> 8, c = hk & 255;
        const float* p = hmpart + ((size_t)(b * 4 + h) * 4) * 256 + c;
        hv[t] = p[0] + p[256] + p[512] + p[768];
    }
    __syncthreads();
    float acc = 0.f;
    const float* w = out_w + (size_t)(kc * 64) * 256 + t;
    #pragma unroll 8
    for (int j = 0; j < 64; j++) acc += hv[j] * w[(size_t)j * 256];
    aspart[(b * 16 + kc) * 256 + t] = acc;
}

// -------- a_s finalize --------
__global__ __launch_bounds__(256) void as_fin(
    const float* __restrict__ aspart, const float* __restrict__ out_b,
    float* __restrict__ a_s)
{
    int b = blockIdx.x, t = threadIdx.x;
    float acc = out_b[t];
    #pragma unroll
    for (int kc = 0; kc < 16; kc++) acc += aspart[(b * 16 + kc) * 256 + t];
    a_s[b * 256 + t] = acc;
}

// -------- mlp layer1: h[b][which][128] = relu(a_s @ w1 + b1); 4-way split-K --------
__global__ __launch_bounds__(256) void mlp1(
    const float* __restrict__ a_s,
    const float* __restrict__ spec_w1, const float* __restrict__ spec_b1,
    const float* __restrict__ spat_w1, const float* __restrict__ spat_b1,
    float* __restrict__ hbuf)
{
    int b = blockIdx.x, which = blockIdx.y, t = threadIdx.x;
    const float* w1 = which ? spat_w1 : spec_w1;
    const float* b1 = which ? spat_b1 : spec_b1;
    __shared__ float as_s[256];
    __shared__ float red[256];
    as_s[t] = a_s[b * 256 + t];
    __syncthreads();
    int o = t & 63, ks = t >> 6;   // 4 k-slices of 64
    #pragma unroll
    for (int p = 0; p < 2; p++) {
        int oo = p * 64 + o;
        float acc = 0.f;
        const float* w = w1 + (size_t)(ks * 64) * 128 + oo;
        #pragma unroll 8
        for (int j = 0; j < 64; j++) acc += as_s[ks * 64 + j] * w[(size_t)j * 128];
        red[t] = acc;
        __syncthreads();
        if (ks == 0) {
            float v = red[o] + red[64 + o] + red[128 + o] + red[192 + o] + b1[oo];
            hbuf[(b * 2 + which) * 128 + oo] = fmaxf(v, 0.f);
        }
        __syncthreads();
    }
}

// -------- mlp layer2 + gate/unc pre-activations: fv[b][head][80]; 3-way split-K --------
__global__ __launch_bounds__(256) void mlp2(
    const float* __restrict__ a_s, const float* __restrict__ hbuf,
    const float* __restrict__ spec_w2, const float* __restrict__ spec_b2,
    const float* __restrict__ spat_w2, const float* __restrict__ spat_b2,
    const float* __restrict__ gate_w, const float* __restrict__ gate_b,
    const float* __restrict__ unc_w, const float* __restrict__ unc_b,
    float* __restrict__ fv)
{
    int b = blockIdx.x, head = blockIdx.y, t = threadIdx.x;
    __shared__ float src[256];
    __shared__ float red[240];
    const float* w; const float* bias; int K;
    if (head == 0)      { w = spec_w2; bias = spec_b2; K = 128; }
    else if (head == 1) { w = spat_w2; bias = spat_b2; K = 128; }
    else if (head == 2) { w = gate_w; bias = gate_b; K = 256; }
    else                { w = unc_w;  bias = unc_b;  K = 256; }
    if (head < 2) { if (t < 128) src[t] = hbuf[(b * 2 + head) * 128 + t]; }
    else src[t] = a_s[b * 256 + t];
    __syncthreads();
    if (t < 240) {
        int o = t % 80, s = t / 80;
        int k0 = (K * s) / 3, k1 = (K * (s + 1)) / 3;
        float acc = 0.f;
        #pragma unroll 8
        for (int k = k0; k < k1; k++) acc += src[k] * w[(size_t)k * 80 + o];
        red[t] = acc;
    }
    __syncthreads();
    if (t < 80) fv[(b * 4 + head) * 80 + t] = red[t] + red[80 + t] + red[160 + t] + bias[t];
}

// -------- final combine (outputs 0..4) --------
__global__ __launch_bounds__(128) void final_comb(
    const float* __restrict__ fv, float* __restrict__ out)
{
    int b = blockIdx.x, t = threadIdx.x;
    __shared__ float alph[80];
    if (t < 80) {
        float sp = fv[(b * 4 + 0) * 80 + t], st = fv[(b * 4 + 1) * 80 + t];
        float gz = fv[(b * 4 + 2) * 80 + t], uz = fv[(b * 4 + 3) * 80 + t];
        float g = 1.f / (1.f + expf(-gz));
        out[b * 80 + t] = g * sp + (1.f - g) * st;
        out[640 + b * 80 + t] = sp;
        out[1280 + b * 80 + t] = st;
        out[1920 + b * 80 + t] = g;
        alph[t] = log1pf(expf(uz)) + 1.f;
    }
    __syncthreads();
    if (t == 0) {
        float s = 0.f;
        for (int l = 0; l < 80; l++) s += alph[l];
        out[2560 + b] = 80.f / s;
    }
}

// ---------------- launcher ----------------
extern "C" void kernel_launch(void* const* d_in, const int* in_sizes, int n_in,
                              void* d_out, int out_size, void* d_ws, size_t ws_size,
                              hipStream_t stream)
{
    (void)in_sizes; (void)n_in; (void)out_size; (void)ws_size;
    const float* c2 = (const float*)d_in[0];
    const float* c3 = (const float*)d_in[1];
    const float* c4 = (const float*)d_in[2];
    const float* c5 = (const float*)d_in[3];
    const float* lat_w0 = (const float*)d_in[4];
    const float* lat_b0 = (const float*)d_in[5];
    const float* lat_w1 = (const float*)d_in[6];
    const float* lat_b1 = (const float*)d_in[7];
    const float* lat_w2 = (const float*)d_in[8];
    const float* lat_b2 = (const float*)d_in[9];
    const float* lat_w3 = (const float*)d_in[10];
    const float* lat_b3 = (const float*)d_in[11];
    const float* sp_w1 = (const float*)d_in[12];
    const float* sp_b1 = (const float*)d_in[13];
    const float* sp_w2 = (const float*)d_in[14];
    const float* sp_b2 = (const float*)d_in[15];
    const float* qkv_w = (const float*)d_in[16];
    const float* qkv_b = (const float*)d_in[17];
    const float* proj_w = (const float*)d_in[18];
    const float* proj_b = (const float*)d_in[19];
    const float* gat_W = (const float*)d_in[20];
    const float* gat_a = (const float*)d_in[21];
    const float* out_w = (const float*)d_in[22];
    const float* out_b = (const float*)d_in[23];
    const float* label_emb = (const float*)d_in[24];
    const float* spec_w1 = (const float*)d_in[25];
    const float* spec_b1 = (const float*)d_in[26];
    const float* spec_w2 = (const float*)d_in[27];
    const float* spec_b2 = (const float*)d_in[28];
    const float* spat_w1 = (const float*)d_in[29];
    const float* spat_b1 = (const float*)d_in[30];
    const float* spat_w2 = (const float*)d_in[31];
    const float* spat_b2 = (const float*)d_in[32];
    const float* gate_w = (const float*)d_in[33];
    const float* gate_b = (const float*)d_in[34];
    const float* unc_w = (const float*)d_in[35];
    const float* unc_b = (const float*)d_in[36];

    float* out = (float*)d_out;
    float* ws = (float*)d_ws;

    // workspace layout (floats); later phases reuse dead regions
    float* pf0    = ws + 0;        // 401408
    float* pf1    = ws + 401408;
    float* pf2    = ws + 1204224;
    float* pf3    = ws + 2809856;  // ends 6021120
    float* pooled = ws + 6021120;  // 16384
    float* beff   = ws + 6037504;  // 2048
    float* swpart = ws + 6039552;  // 32768
    float* qkv    = ws + 0;        // reuses pf0/pf1 (dead after lateral)
    float* S      = ws + 1204224;  // reuses pf2/pf3
    float* xo     = ws + 3662848;  // 401408
    float* lf     = ws + 4064256;  // 163840 (ends 4228096)
    float* Wa     = ws + 4228096;  // 2048
    float* xopart = ws + 4230144;  // 14336
    float* gpart  = ws + 4244480;  // 8192
    float* s12    = ws + 4252672;  // 5120
    float* amlf   = ws + 4257792;  // 8192
    float* hmpart = ws + 4265984;  // 32768
    float* aspart = ws + 4298752;  // 32768 (ends 4331520)
    float* a_sb   = ws + 4331520;  // 2048
    float* hbuf   = ws + 4333568;  // 2048
    float* fv     = ws + 4335616;  // 2560 (ends 4338176)
    float* xtok   = ws + 6106112;  // 401408

    float* swp  = out + 2568;  // sw [8,4] (output 5)
    float* atts = out + 2600;  // atts [4,8,80,80] (output 6)

    // 1. pool features of all scales to 14x14 (+ c5 global mean)
    pool_elem<112, 256, 8><<<1568, 256, 0, stream>>>(c2, pf0);
    pool_elem<56, 512, 6><<<3136, 256, 0, stream>>>(c3, pf1);
    pool_elem<28, 1024, 4><<<6272, 256, 0, stream>>>(c4, pf2);
    pool_elem<14, 2048, 3><<<12544, 256, 0, stream>>>(c5, pf3);
    c5_mean<<<4096, 256, 0, stream>>>(c5, pooled);
    // 2. scale weights + effective bias (split-K)
    sw_part<<<dim3(8, 8), 512, 0, stream>>>(pooled, sp_w1, swpart);
    sw_fin<<<8, 512, 0, stream>>>(swpart, sp_b1, sp_w2, sp_b2,
                                  lat_b0, lat_b1, lat_b2, lat_b3, swp, beff);
    // 3. lateral projection + sw combine -> x tokens [1568,256]
    xtok_init<<<1568, 256, 0, stream>>>(beff, xtok);
    lateral_slice<<<dim3(196, 8), 256, 0, stream>>>(pf0, pf1, pf2, pf3,
                                                    lat_w0, lat_w1, lat_w2, lat_w3,
                                                    swp, xtok);
    // 4. qkv = x @ qkv_w + qkv_b : [1568,768]
    gemm_kernel<true><<<dim3(49 * 12, 1, 1), 256, 0, stream>>>(
        xtok, 256, 0, 0, qkv_w, 768, 0, 0, qkv, 768, 0, 0,
        qkv_b, 1568, 768, 256, 1.f, 49);
    // 5. S = q @ k^T * hd^-0.5, per (b,h) : [64,196,196]
    gemm_kernel<false><<<dim3(7 * 4, 8, 8), 256, 0, stream>>>(
        qkv, 768, 150528, 32, qkv + 256, 768, 150528, 32,
        S, 196, 307328, 38416, nullptr, 196, 196, 32, 0.17677669529663687f, 7);
    // 6. row softmax on S (in place)
    attn_softmax<<<3136, 256, 0, stream>>>(S);
    // 7. xo = P @ v : [1568,256] (head-concat layout)
    gemm_kernel<true><<<dim3(7, 8, 8), 256, 0, stream>>>(
        S, 196, 307328, 38416, qkv + 512, 768, 150528, 32,
        xo, 256, 50176, 32, nullptr, 196, 32, 196, 1.f, 7);
    // 8. gctx (mean-commuted proj), split-K parallel
    xo_part<<<dim3(8, 7), 256, 0, stream>>>(xo, xopart);
    gctx_part<<<dim3(8, 4), 256, 0, stream>>>(xopart, proj_w, gpart);
    // 9. Wa = gat_W rows . a-halves (independent of lf chain)
    wa2<<<dim3(4, 4), 256, 0, stream>>>(gat_W, gat_a, Wa);
    // 10. fused lf + GAT scores, then row softmax -> atts (output 6)
    lf_s12<<<dim3(80, 8), 256, 0, stream>>>(gpart, proj_b, label_emb, Wa, lf, s12);
    gat_rows<<<dim3(8, 4, 20), 256, 0, stream>>>(s12, atts);
    // 11. tail: attmean/amlf -> hm partials -> a_s partials -> a_s
    amlf_kernel<<<dim3(8, 4), 256, 0, stream>>>(atts, lf, amlf);
    hm_part<<<dim3(8, 4, 4), 256, 0, stream>>>(amlf, gat_W, hmpart);
    as_part<<<dim3(8, 16), 256, 0, stream>>>(hmpart, out_w, aspart);
    as_fin<<<8, 256, 0, stream>>>(aspart, out_b, a_sb);
    // 12. final heads (outputs 0..4), split-K parallel
    mlp1<<<dim3(8, 2), 256, 0, stream>>>(a_sb, spec_w1, spec_b1, spat_w1, spat_b1, hbuf);
    mlp2<<<dim3(8, 4), 256, 0, stream>>>(a_sb, hbuf,
        spec_w2, spec_b2, spat_w2, spat_b2,
        gate_w, gate_b, unc_w, unc_b, fv);
    final_comb<<<8, 128, 0, stream>>>(fv, out);
}